// Round 18
// baseline (170.661 us; speedup 1.0000x reference)
//
#include <hip/hip_runtime.h>
#include <hip/hip_bf16.h>

#define LRELU(x) ((x) > 0.f ? (x) : 0.2f * (x))
#define LOG2E 1.44269504088896340736f
#define EXP2F(x) __builtin_amdgcn_exp2f(x)
#define BSH 8          // bucket = 256 consecutive dst nodes (requires N < 131072)
#define EPB 4096       // edges per block in bucket phases

__device__ inline float bf_lo(unsigned w) { return __uint_as_float(w << 16); }
__device__ inline float bf_hi(unsigned w) { return __uint_as_float(w & 0xffff0000u); }
__device__ inline unsigned short f2bf(float f) {   // round-to-nearest-even bf16
    unsigned u = __float_as_uint(f);
    unsigned r = u + 0x7fffu + ((u >> 16) & 1u);
    return (unsigned short)(r >> 16);
}

// ---------------- Bucketed CSR build (5 launches total) ----------------
// Edge packing: bits [0,17) = src, bits [17,25) = dst & 255; bucket implicit in slab.

__global__ void bucket_hist_kernel(const int* __restrict__ dst, int* __restrict__ bhist,
                                   int E, int NB) {
    __shared__ int cnt[256];
    int t = threadIdx.x;
    cnt[t] = 0;
    __syncthreads();
    int e0 = blockIdx.x * EPB + t;
#pragma unroll
    for (int i = 0; i < EPB / 256; ++i) {
        int e = e0 + i * 256;
        if (e < E) atomicAdd(&cnt[dst[e] >> BSH], 1);
    }
    __syncthreads();
    if (t < NB && cnt[t]) atomicAdd(&bhist[t], cnt[t]);
}

__global__ void bucket_scan_kernel(const int* __restrict__ bhist, int* __restrict__ boff,
                                   int* __restrict__ bcur, int NB) {
    int t = threadIdx.x;
    int v = (t < NB) ? bhist[t] : 0;
    int lane = t & 63, wid = t >> 6;
    int x = v;
#pragma unroll
    for (int off = 1; off < 64; off <<= 1) {
        int y = __shfl_up(x, off, 64);
        if (lane >= off) x += y;
    }
    __shared__ int sw[4], sw2[4];
    if (lane == 63) sw[wid] = x;
    __syncthreads();
    if (t == 0) { int a = 0; for (int w = 0; w < 4; ++w) { sw2[w] = a; a += sw[w]; } }
    __syncthreads();
    int excl = x - v + sw2[wid];
    if (t < NB) { boff[t] = excl; bcur[t] = excl; }
    if (t == NB - 1) boff[NB] = excl + v;   // == E
}

__global__ void bucket_scatter_kernel(const int* __restrict__ src, const int* __restrict__ dst,
                                      int* __restrict__ bcur, unsigned* __restrict__ ebuf, int E) {
    __shared__ int cnt[256];
    __shared__ int base[256];
    int t = threadIdx.x;
    cnt[t] = 0;
    __syncthreads();
    unsigned pk[EPB / 256];
    int bb[EPB / 256];
    int e0 = blockIdx.x * EPB + t;
#pragma unroll
    for (int i = 0; i < EPB / 256; ++i) {
        int e = e0 + i * 256;
        int b = -1; unsigned p = 0;
        if (e < E) {
            int s = src[e], d = dst[e];
            b = d >> BSH;
            p = (unsigned)s | ((unsigned)(d & ((1 << BSH) - 1)) << 17);
            atomicAdd(&cnt[b], 1);
        }
        bb[i] = b; pk[i] = p;
    }
    __syncthreads();
    if (cnt[t]) base[t] = atomicAdd(&bcur[t], cnt[t]);
    __syncthreads();
    cnt[t] = 0;
    __syncthreads();
#pragma unroll
    for (int i = 0; i < EPB / 256; ++i) {
        if (bb[i] >= 0) {
            int pos = base[bb[i]] + atomicAdd(&cnt[bb[i]], 1);
            ebuf[pos] = pk[i];
        }
    }
}

// One block per bucket: count per-node degrees, in-block exclusive scan
// (rowstart[node] = boff[b] + excl), then scatter colv with LDS cursors.
__global__ void build_csr_kernel(const unsigned* __restrict__ ebuf, const int* __restrict__ boff,
                                 int* __restrict__ rowstart, int* __restrict__ colv,
                                 int n, int E) {
    __shared__ int cnt[256];
    __shared__ int sw[4], sw2[4];
    int t = threadIdx.x, b = blockIdx.x;
    cnt[t] = 0;
    __syncthreads();
    int beg = boff[b], end = boff[b + 1];
    for (int j = beg + t; j < end; j += 256)
        atomicAdd(&cnt[(ebuf[j] >> 17) & 255], 1);
    __syncthreads();
    int v = cnt[t];
    int lane = t & 63, wid = t >> 6;
    int x = v;
#pragma unroll
    for (int off = 1; off < 64; off <<= 1) {
        int y = __shfl_up(x, off, 64);
        if (lane >= off) x += y;
    }
    if (lane == 63) sw[wid] = x;
    __syncthreads();
    if (t == 0) { int a = 0; for (int w = 0; w < 4; ++w) { sw2[w] = a; a += sw[w]; } }
    __syncthreads();
    int excl = x - v + sw2[wid] + beg;
    int node = (b << BSH) + t;
    if (node < n) rowstart[node] = excl;
    if (node == n - 1) rowstart[n] = E;
    __syncthreads();
    cnt[t] = excl;      // reuse as cursor
    __syncthreads();
    for (int j = beg + t; j < end; j += 256) {
        unsigned p = ebuf[j];
        int dlow = (p >> 17) & 255;
        int s = (int)(p & 0x1FFFF);
        int pos = atomicAdd(&cnt[dlow], 1);
        colv[pos] = s;
    }
}

// ---------------- proj1: h(bf16) = x @ W1 (+ fused logits, pre-scaled by log2e) --------

template <int K>
__global__ __launch_bounds__(256, 6) void proj_kernel(
        const float* __restrict__ x, const float* __restrict__ W,
        const float* __restrict__ a_src, const float* __restrict__ a_dst,
        __hip_bfloat16* __restrict__ h, float* __restrict__ as_out,
        float* __restrict__ ad_out, int n) {
    __shared__ unsigned Wtp[64 * (K / 2 + 1)];   // [col][kk] bf16x2, stride K/2+1
    __shared__ float xsh[16 * K];                // 16-row chunk (fp32)

    for (int i = threadIdx.x; i < (K / 2) * 64; i += 256) {
        int kk = i >> 6, c = i & 63;            // coalesced W reads
        unsigned short lo = f2bf(W[(2 * kk) * 64 + c]);
        unsigned short hi = f2bf(W[(2 * kk + 1) * 64 + c]);
        Wtp[c * (K / 2 + 1) + kk] = (unsigned)lo | ((unsigned)hi << 16);
    }

    int lane = threadIdx.x & 63, wid = threadIdx.x >> 6;
    float as_l = a_src[lane] * LOG2E, ad_l = a_dst[lane] * LOG2E;  // exp2 trick
    const float4* x4 = reinterpret_cast<const float4*>(x);
    float4* xsh4 = reinterpret_cast<float4*>(xsh);
    const int K4 = K / 4;
    int nchunk = (n + 15) >> 4;

    for (int ci = blockIdx.x; ci < nchunk; ci += gridDim.x) {
        int base = ci * 16;
        __syncthreads();
        for (int j = threadIdx.x; j < 16 * K4; j += 256) {
            int row = j / K4;
            int r = base + row;
            float4 v = make_float4(0.f, 0.f, 0.f, 0.f);
            if (r < n) v = x4[(size_t)r * K4 + (j - row * K4)];
            xsh4[j] = v;
        }
        __syncthreads();

        int r0 = base + wid * 4;
        float acc0 = 0.f, acc1 = 0.f, acc2 = 0.f, acc3 = 0.f;
        const unsigned* wl = Wtp + lane * (K / 2 + 1);
#pragma unroll 4
        for (int k4 = 0; k4 < K4; ++k4) {
            float4 va = xsh4[(wid * 4 + 0) * K4 + k4];
            float4 vb = xsh4[(wid * 4 + 1) * K4 + k4];
            float4 vc = xsh4[(wid * 4 + 2) * K4 + k4];
            float4 vd = xsh4[(wid * 4 + 3) * K4 + k4];
            unsigned wp0 = wl[2 * k4], wp1 = wl[2 * k4 + 1];
            float w0 = bf_lo(wp0), w1 = bf_hi(wp0);
            float w2 = bf_lo(wp1), w3 = bf_hi(wp1);
            acc0 = fmaf(va.x, w0, acc0); acc0 = fmaf(va.y, w1, acc0);
            acc0 = fmaf(va.z, w2, acc0); acc0 = fmaf(va.w, w3, acc0);
            acc1 = fmaf(vb.x, w0, acc1); acc1 = fmaf(vb.y, w1, acc1);
            acc1 = fmaf(vb.z, w2, acc1); acc1 = fmaf(vb.w, w3, acc1);
            acc2 = fmaf(vc.x, w0, acc2); acc2 = fmaf(vc.y, w1, acc2);
            acc2 = fmaf(vc.z, w2, acc2); acc2 = fmaf(vc.w, w3, acc2);
            acc3 = fmaf(vd.x, w0, acc3); acc3 = fmaf(vd.y, w1, acc3);
            acc3 = fmaf(vd.z, w2, acc3); acc3 = fmaf(vd.w, w3, acc3);
        }
        if (r0 + 0 < n) h[(size_t)(r0 + 0) * 64 + lane] = __float2bfloat16(acc0);
        if (r0 + 1 < n) h[(size_t)(r0 + 1) * 64 + lane] = __float2bfloat16(acc1);
        if (r0 + 2 < n) h[(size_t)(r0 + 2) * 64 + lane] = __float2bfloat16(acc2);
        if (r0 + 3 < n) h[(size_t)(r0 + 3) * 64 + lane] = __float2bfloat16(acc3);
        float s0 = acc0 * as_l, d0 = acc0 * ad_l;
        float s1 = acc1 * as_l, d1 = acc1 * ad_l;
        float s2 = acc2 * as_l, d2 = acc2 * ad_l;
        float s3 = acc3 * as_l, d3 = acc3 * ad_l;
#pragma unroll
        for (int off = 32; off; off >>= 1) {
            s0 += __shfl_xor(s0, off, 64); d0 += __shfl_xor(d0, off, 64);
            s1 += __shfl_xor(s1, off, 64); d1 += __shfl_xor(d1, off, 64);
            s2 += __shfl_xor(s2, off, 64); d2 += __shfl_xor(d2, off, 64);
            s3 += __shfl_xor(s3, off, 64); d3 += __shfl_xor(d3, off, 64);
        }
        if (lane == 0) {
            if (r0 + 0 < n) { as_out[r0 + 0] = s0; ad_out[r0 + 0] = d0; }
            if (r0 + 1 < n) { as_out[r0 + 1] = s1; ad_out[r0 + 1] = d1; }
            if (r0 + 2 < n) { as_out[r0 + 2] = s2; ad_out[r0 + 2] = d2; }
            if (r0 + 3 < n) { as_out[r0 + 3] = s3; ad_out[r0 + 3] = d3; }
        }
    }
}

// ---------------- proj2: h2(bf16) = z1(packed bf16) @ W2 (+ fused logits) ----------------

__global__ __launch_bounds__(256, 6) void proj2_kernel(
        const unsigned* __restrict__ z1p, const float* __restrict__ W,
        const float* __restrict__ a_src, const float* __restrict__ a_dst,
        __hip_bfloat16* __restrict__ h, float* __restrict__ as_out,
        float* __restrict__ ad_out, int n) {
    const int K = 64;
    __shared__ unsigned Wtp[64 * 33];   // [col][kk] bf16x2, stride 33 (conflict-free)
    __shared__ float xsh[16 * K];       // 16-row z1 chunk, unpacked to fp32

    for (int i = threadIdx.x; i < 32 * 64; i += 256) {
        int kk = i >> 6, c = i & 63;
        unsigned short lo = f2bf(W[(2 * kk) * 64 + c]);
        unsigned short hi = f2bf(W[(2 * kk + 1) * 64 + c]);
        Wtp[c * 33 + kk] = (unsigned)lo | ((unsigned)hi << 16);
    }

    int lane = threadIdx.x & 63, wid = threadIdx.x >> 6;
    float as_l = a_src[lane] * LOG2E, ad_l = a_dst[lane] * LOG2E;
    float4* xsh4 = reinterpret_cast<float4*>(xsh);
    const int K4 = K / 4;
    int nchunk = (n + 15) >> 4;

    for (int ci = blockIdx.x; ci < nchunk; ci += gridDim.x) {
        int base = ci * 16;
        __syncthreads();
        // stage 16 rows of packed z1 (u32 = 2 bf16), unpack to fp32
        for (int j = threadIdx.x; j < 16 * 32; j += 256) {
            int row = j >> 5, c2 = j & 31;
            int r = base + row;
            unsigned pv = (r < n) ? z1p[(size_t)r * 32 + c2] : 0u;
            xsh[row * K + 2 * c2]     = bf_lo(pv);
            xsh[row * K + 2 * c2 + 1] = bf_hi(pv);
        }
        __syncthreads();

        int r0 = base + wid * 4;
        float acc0 = 0.f, acc1 = 0.f, acc2 = 0.f, acc3 = 0.f;
        const unsigned* wl = Wtp + lane * 33;
#pragma unroll 4
        for (int k4 = 0; k4 < K4; ++k4) {
            float4 va = xsh4[(wid * 4 + 0) * K4 + k4];
            float4 vb = xsh4[(wid * 4 + 1) * K4 + k4];
            float4 vc = xsh4[(wid * 4 + 2) * K4 + k4];
            float4 vd = xsh4[(wid * 4 + 3) * K4 + k4];
            unsigned wp0 = wl[2 * k4], wp1 = wl[2 * k4 + 1];
            float w0 = bf_lo(wp0), w1 = bf_hi(wp0);
            float w2 = bf_lo(wp1), w3 = bf_hi(wp1);
            acc0 = fmaf(va.x, w0, acc0); acc0 = fmaf(va.y, w1, acc0);
            acc0 = fmaf(va.z, w2, acc0); acc0 = fmaf(va.w, w3, acc0);
            acc1 = fmaf(vb.x, w0, acc1); acc1 = fmaf(vb.y, w1, acc1);
            acc1 = fmaf(vb.z, w2, acc1); acc1 = fmaf(vb.w, w3, acc1);
            acc2 = fmaf(vc.x, w0, acc2); acc2 = fmaf(vc.y, w1, acc2);
            acc2 = fmaf(vc.z, w2, acc2); acc2 = fmaf(vc.w, w3, acc2);
            acc3 = fmaf(vd.x, w0, acc3); acc3 = fmaf(vd.y, w1, acc3);
            acc3 = fmaf(vd.z, w2, acc3); acc3 = fmaf(vd.w, w3, acc3);
        }
        if (r0 + 0 < n) h[(size_t)(r0 + 0) * 64 + lane] = __float2bfloat16(acc0);
        if (r0 + 1 < n) h[(size_t)(r0 + 1) * 64 + lane] = __float2bfloat16(acc1);
        if (r0 + 2 < n) h[(size_t)(r0 + 2) * 64 + lane] = __float2bfloat16(acc2);
        if (r0 + 3 < n) h[(size_t)(r0 + 3) * 64 + lane] = __float2bfloat16(acc3);
        float s0 = acc0 * as_l, d0 = acc0 * ad_l;
        float s1 = acc1 * as_l, d1 = acc1 * ad_l;
        float s2 = acc2 * as_l, d2 = acc2 * ad_l;
        float s3 = acc3 * as_l, d3 = acc3 * ad_l;
#pragma unroll
        for (int off = 32; off; off >>= 1) {
            s0 += __shfl_xor(s0, off, 64); d0 += __shfl_xor(d0, off, 64);
            s1 += __shfl_xor(s1, off, 64); d1 += __shfl_xor(d1, off, 64);
            s2 += __shfl_xor(s2, off, 64); d2 += __shfl_xor(d2, off, 64);
            s3 += __shfl_xor(s3, off, 64); d3 += __shfl_xor(d3, off, 64);
        }
        if (lane == 0) {
            if (r0 + 0 < n) { as_out[r0 + 0] = s0; ad_out[r0 + 0] = d0; }
            if (r0 + 1 < n) { as_out[r0 + 1] = s1; ad_out[r0 + 1] = d1; }
            if (r0 + 2 < n) { as_out[r0 + 2] = s2; ad_out[r0 + 2] = d2; }
            if (r0 + 3 < n) { as_out[r0 + 3] = s3; ad_out[r0 + 3] = d3; }
        }
    }
}

// ---------------- Core quarter-wave agg loop ----------------
// 16 lanes per edge; lane owns 4 features (uint2 = 2 bf16-pairs). One wave-instruction
// covers 4 edges (vs 2 in half-wave): ~2x fewer VALU+VMEM instructions per edge.
// q = lane>>4 (edge slot in group of 4), fl8 = lane&15 (feature quad index).

__device__ inline void agg_core(const unsigned* __restrict__ h32, const float* __restrict__ as_in,
                                float ad_n, int node, int beg, int end, int q, int fl8,
                                const int* __restrict__ colv, float& denom, float4& acc) {
    denom = 0.f;
    acc = make_float4(0.f, 0.f, 0.f, 0.f);
    const uint2* h64 = reinterpret_cast<const uint2*>(h32);   // row pitch = 16 uint2
    if (q == 0) {    // self-loop handled by edge-slot 0
        float ex = EXP2F(LRELU(as_in[node] + ad_n));
        uint2 hw = h64[(unsigned)node * 16u + fl8];
        denom = ex;
        acc.x = bf_lo(hw.x) * ex; acc.y = bf_hi(hw.x) * ex;
        acc.z = bf_lo(hw.y) * ex; acc.w = bf_hi(hw.y) * ex;
    }
#define QSTEP(s_)                                                   \
    {                                                               \
        bool valid_ = (s_) >= 0;                                    \
        int ss_ = valid_ ? (s_) : node;                             \
        float a_ = as_in[ss_];                                      \
        uint2 hw_ = h64[(unsigned)ss_ * 16u + fl8];                 \
        float w_ = valid_ ? EXP2F(LRELU(a_ + ad_n)) : 0.f;          \
        denom += w_;                                                \
        acc.x = fmaf(bf_lo(hw_.x), w_, acc.x);                      \
        acc.y = fmaf(bf_hi(hw_.x), w_, acc.y);                      \
        acc.z = fmaf(bf_lo(hw_.y), w_, acc.z);                      \
        acc.w = fmaf(bf_hi(hw_.y), w_, acc.w);                      \
    }
    int i = beg;
    int pre = (beg + 3) & ~3;
    if (pre > end) pre = end;
    if (i < pre) {   // up to 3 unaligned head edges, one per edge-slot
        int cnt = pre - i;
        int s = (q < cnt) ? colv[i + q] : -1;
        QSTEP(s);
        i = pre;
    }
    for (; i + 7 < end; i += 8) {   // 8 edges = 2 aligned int4 loads
        int4 cA = *reinterpret_cast<const int4*>(colv + i);
        int4 cB = *reinterpret_cast<const int4*>(colv + i + 4);
        int sA = q == 0 ? cA.x : q == 1 ? cA.y : q == 2 ? cA.z : cA.w;
        int sB = q == 0 ? cB.x : q == 1 ? cB.y : q == 2 ? cB.z : cB.w;
        float aA = as_in[sA], aB = as_in[sB];
        uint2 hA = h64[(unsigned)sA * 16u + fl8];
        uint2 hB = h64[(unsigned)sB * 16u + fl8];
        float wA = EXP2F(LRELU(aA + ad_n));
        float wB = EXP2F(LRELU(aB + ad_n));
        denom += wA + wB;
        acc.x = fmaf(bf_lo(hA.x), wA, acc.x); acc.y = fmaf(bf_hi(hA.x), wA, acc.y);
        acc.z = fmaf(bf_lo(hA.y), wA, acc.z); acc.w = fmaf(bf_hi(hA.y), wA, acc.w);
        acc.x = fmaf(bf_lo(hB.x), wB, acc.x); acc.y = fmaf(bf_hi(hB.x), wB, acc.y);
        acc.z = fmaf(bf_lo(hB.y), wB, acc.z); acc.w = fmaf(bf_hi(hB.y), wB, acc.w);
    }
    for (; i + 3 < end; i += 4) {   // 4 edges = 1 aligned int4 load
        int4 cA = *reinterpret_cast<const int4*>(colv + i);
        int sA = q == 0 ? cA.x : q == 1 ? cA.y : q == 2 ? cA.z : cA.w;
        float aA = as_in[sA];
        uint2 hA = h64[(unsigned)sA * 16u + fl8];
        float wA = EXP2F(LRELU(aA + ad_n));
        denom += wA;
        acc.x = fmaf(bf_lo(hA.x), wA, acc.x); acc.y = fmaf(bf_hi(hA.x), wA, acc.y);
        acc.z = fmaf(bf_lo(hA.y), wA, acc.z); acc.w = fmaf(bf_hi(hA.y), wA, acc.w);
    }
    if (i < end) {   // up to 3 tail edges
        int cnt = end - i;
        int s = (q < cnt) ? colv[i + q] : -1;
        QSTEP(s);
    }
#undef QSTEP
    // combine the 4 edge-slots
    denom += __shfl_xor(denom, 16, 64); denom += __shfl_xor(denom, 32, 64);
    acc.x += __shfl_xor(acc.x, 16, 64); acc.x += __shfl_xor(acc.x, 32, 64);
    acc.y += __shfl_xor(acc.y, 16, 64); acc.y += __shfl_xor(acc.y, 32, 64);
    acc.z += __shfl_xor(acc.z, 16, 64); acc.z += __shfl_xor(acc.z, 32, 64);
    acc.w += __shfl_xor(acc.w, 16, 64); acc.w += __shfl_xor(acc.w, 32, 64);
}

// ---------------- agg1: softmax-agg + bias + ELU -> packed bf16 z1 ----------------

__global__ void agg1_kernel(const unsigned* __restrict__ h32, const float* __restrict__ as_in,
                            const float* __restrict__ ad_in, const int* __restrict__ rowstart,
                            const int* __restrict__ colv, const float* __restrict__ bias,
                            unsigned* __restrict__ z1p, int n) {
    int node = blockIdx.x * 4 + (int)(threadIdx.x >> 6);
    int lane = threadIdx.x & 63;
    if (node >= n) return;
    int q = lane >> 4, fl8 = lane & 15;

    float ad_n = ad_in[node];
    int beg = rowstart[node], end = rowstart[node + 1];
    float denom; float4 acc;
    agg_core(h32, as_in, ad_n, node, beg, end, q, fl8, colv, denom, acc);

    if (q == 0) {
        float4 bv = *reinterpret_cast<const float4*>(bias + 4 * fl8);
        float o0 = acc.x / denom + bv.x;
        float o1 = acc.y / denom + bv.y;
        float o2 = acc.z / denom + bv.z;
        float o3 = acc.w / denom + bv.w;
        o0 = o0 > 0.f ? o0 : __expf(o0) - 1.f;   // ELU
        o1 = o1 > 0.f ? o1 : __expf(o1) - 1.f;
        o2 = o2 > 0.f ? o2 : __expf(o2) - 1.f;
        o3 = o3 > 0.f ? o3 : __expf(o3) - 1.f;
        uint2 zw;
        zw.x = (unsigned)f2bf(o0) | ((unsigned)f2bf(o1) << 16);
        zw.y = (unsigned)f2bf(o2) | ((unsigned)f2bf(o3) << 16);
        reinterpret_cast<uint2*>(z1p)[(size_t)node * 16 + fl8] = zw;
    }
}

// ---------------- agg2: softmax-agg + bias -> final fp32 output ----------------

__global__ void agg2_kernel(const unsigned* __restrict__ h32, const float* __restrict__ as_in,
                            const float* __restrict__ ad_in, const int* __restrict__ rowstart,
                            const int* __restrict__ colv, const float* __restrict__ bias,
                            float* __restrict__ out, int n) {
    int node = blockIdx.x * 4 + (int)(threadIdx.x >> 6);
    int lane = threadIdx.x & 63;
    if (node >= n) return;
    int q = lane >> 4, fl8 = lane & 15;

    float ad_n = ad_in[node];
    int beg = rowstart[node], end = rowstart[node + 1];
    float denom; float4 acc;
    agg_core(h32, as_in, ad_n, node, beg, end, q, fl8, colv, denom, acc);

    if (q == 0) {
        float4 bv = *reinterpret_cast<const float4*>(bias + 4 * fl8);
        float4 o;
        o.x = acc.x / denom + bv.x;
        o.y = acc.y / denom + bv.y;
        o.z = acc.z / denom + bv.z;
        o.w = acc.w / denom + bv.w;
        *reinterpret_cast<float4*>(out + (size_t)node * 64 + 4 * fl8) = o;
    }
}

// ---------------- Launch ----------------

extern "C" void kernel_launch(void* const* d_in, const int* in_sizes, int n_in,
                              void* d_out, int out_size, void* d_ws, size_t ws_size,
                              hipStream_t stream) {
    const float* x    = (const float*)d_in[0];
    const int*   eidx = (const int*)d_in[1];   // [2, E] flat
    const float* W1   = (const float*)d_in[2];
    const float* aS1  = (const float*)d_in[3];
    const float* aD1  = (const float*)d_in[4];
    const float* b1   = (const float*)d_in[5];
    const float* W2   = (const float*)d_in[6];
    const float* aS2  = (const float*)d_in[7];
    const float* aD2  = (const float*)d_in[8];
    const float* b2   = (const float*)d_in[9];
    float* out = (float*)d_out;

    const int F = 128, H = 64;
    const int N = in_sizes[0] / F;
    const int E = in_sizes[1] / 2;
    const int* src = eidx;
    const int* dst = eidx + E;

    // workspace carve-up
    char* p = (char*)d_ws;
    __hip_bfloat16* hbuf = (__hip_bfloat16*)p;  p += (size_t)N * H * sizeof(__hip_bfloat16);
    __hip_bfloat16* h2b  = (__hip_bfloat16*)p;  p += (size_t)N * H * sizeof(__hip_bfloat16);
    unsigned* z1p = (unsigned*)p;         p += (size_t)N * (H / 2) * sizeof(unsigned);
    float* as_b  = (float*)p;             p += (size_t)N * sizeof(float);
    float* ad_b  = (float*)p;             p += (size_t)N * sizeof(float);
    float* as2_b = (float*)p;             p += (size_t)N * sizeof(float);
    float* ad2_b = (float*)p;             p += (size_t)N * sizeof(float);
    int* rowstart = (int*)p;              p += (size_t)(N + 4) * sizeof(int);  // pad -> colv 16B-aligned
    int* colv     = (int*)p;              p += (size_t)E * sizeof(int);
    int NB = (N + (1 << BSH) - 1) >> BSH;           // buckets (<= 256)
    int* bhist  = (int*)p;                p += (size_t)NB * sizeof(int);
    int* boff   = (int*)p;                p += (size_t)(NB + 1) * sizeof(int);
    int* bcur   = (int*)p;                p += (size_t)NB * sizeof(int);
    // ebuf aliases hbuf (E*4 B <= N*H*2 B): CSR build fully precedes proj1's h writes.
    unsigned* ebuf = (unsigned*)hbuf;

    int ngrid4 = (N + 3) / 4;
    int nbE = (E + EPB - 1) / EPB;
    int nchunk = (N + 15) / 16;
    int pgrid = nchunk < 1536 ? nchunk : 1536;   // persistent, 6 blocks/CU

    // --- bucketed CSR build (5 launches) ---
    (void)hipMemsetAsync(bhist, 0, (size_t)NB * sizeof(int), stream);
    hipLaunchKernelGGL(bucket_hist_kernel, dim3(nbE), dim3(256), 0, stream, dst, bhist, E, NB);
    hipLaunchKernelGGL(bucket_scan_kernel, dim3(1), dim3(256), 0, stream, bhist, boff, bcur, NB);
    hipLaunchKernelGGL(bucket_scatter_kernel, dim3(nbE), dim3(256), 0, stream, src, dst, bcur, ebuf, E);
    hipLaunchKernelGGL(build_csr_kernel, dim3(NB), dim3(256), 0, stream, ebuf, boff, rowstart, colv, N, E);

    // --- layer 1 ---
    hipLaunchKernelGGL((proj_kernel<128>), dim3(pgrid), dim3(256), 0, stream,
                       x, W1, aS1, aD1, hbuf, as_b, ad_b, N);
    hipLaunchKernelGGL(agg1_kernel, dim3(ngrid4), dim3(256), 0, stream,
                       (const unsigned*)hbuf, as_b, ad_b, rowstart, colv, b1, z1p, N);

    // --- layer 2 ---
    hipLaunchKernelGGL(proj2_kernel, dim3(pgrid), dim3(256), 0, stream,
                       z1p, W2, aS2, aD2, h2b, as2_b, ad2_b, N);
    hipLaunchKernelGGL(agg2_kernel, dim3(ngrid4), dim3(256), 0, stream,
                       (const unsigned*)h2b, as2_b, ad2_b, rowstart, colv, b2, out, N);
}

// Round 19
// 146.193 us; speedup vs baseline: 1.1674x; 1.1674x over previous
//
#include <hip/hip_runtime.h>
#include <hip/hip_bf16.h>

#define LRELU(x) ((x) > 0.f ? (x) : 0.2f * (x))
#define LOG2E 1.44269504088896340736f
#define EXP2F(x) __builtin_amdgcn_exp2f(x)
#define BSH 8          // bucket = 256 consecutive dst nodes (requires N < 131072)
#define EPB 4096       // edges per block in bucket phases

typedef __attribute__((ext_vector_type(8))) short bf16x8;   // MFMA A/B fragment
typedef __attribute__((ext_vector_type(4))) float f32x4;    // MFMA C/D fragment

__device__ inline float bf_lo(unsigned w) { return __uint_as_float(w << 16); }
__device__ inline float bf_hi(unsigned w) { return __uint_as_float(w & 0xffff0000u); }
__device__ inline unsigned short f2bf(float f) {   // round-to-nearest-even bf16
    unsigned u = __float_as_uint(f);
    unsigned r = u + 0x7fffu + ((u >> 16) & 1u);
    return (unsigned short)(r >> 16);
}

// ---------------- Bucketed CSR build (5 launches total) ----------------

__global__ void bucket_hist_kernel(const int* __restrict__ dst, int* __restrict__ bhist,
                                   int E, int NB) {
    __shared__ int cnt[256];
    int t = threadIdx.x;
    cnt[t] = 0;
    __syncthreads();
    int e0 = blockIdx.x * EPB + t;
#pragma unroll
    for (int i = 0; i < EPB / 256; ++i) {
        int e = e0 + i * 256;
        if (e < E) atomicAdd(&cnt[dst[e] >> BSH], 1);
    }
    __syncthreads();
    if (t < NB && cnt[t]) atomicAdd(&bhist[t], cnt[t]);
}

__global__ void bucket_scan_kernel(const int* __restrict__ bhist, int* __restrict__ boff,
                                   int* __restrict__ bcur, int NB) {
    int t = threadIdx.x;
    int v = (t < NB) ? bhist[t] : 0;
    int lane = t & 63, wid = t >> 6;
    int x = v;
#pragma unroll
    for (int off = 1; off < 64; off <<= 1) {
        int y = __shfl_up(x, off, 64);
        if (lane >= off) x += y;
    }
    __shared__ int sw[4], sw2[4];
    if (lane == 63) sw[wid] = x;
    __syncthreads();
    if (t == 0) { int a = 0; for (int w = 0; w < 4; ++w) { sw2[w] = a; a += sw[w]; } }
    __syncthreads();
    int excl = x - v + sw2[wid];
    if (t < NB) { boff[t] = excl; bcur[t] = excl; }
    if (t == NB - 1) boff[NB] = excl + v;   // == E
}

__global__ void bucket_scatter_kernel(const int* __restrict__ src, const int* __restrict__ dst,
                                      int* __restrict__ bcur, unsigned* __restrict__ ebuf, int E) {
    __shared__ int cnt[256];
    __shared__ int base[256];
    int t = threadIdx.x;
    cnt[t] = 0;
    __syncthreads();
    unsigned pk[EPB / 256];
    int bb[EPB / 256];
    int e0 = blockIdx.x * EPB + t;
#pragma unroll
    for (int i = 0; i < EPB / 256; ++i) {
        int e = e0 + i * 256;
        int b = -1; unsigned p = 0;
        if (e < E) {
            int s = src[e], d = dst[e];
            b = d >> BSH;
            p = (unsigned)s | ((unsigned)(d & ((1 << BSH) - 1)) << 17);
            atomicAdd(&cnt[b], 1);
        }
        bb[i] = b; pk[i] = p;
    }
    __syncthreads();
    if (cnt[t]) base[t] = atomicAdd(&bcur[t], cnt[t]);
    __syncthreads();
    cnt[t] = 0;
    __syncthreads();
#pragma unroll
    for (int i = 0; i < EPB / 256; ++i) {
        if (bb[i] >= 0) {
            int pos = base[bb[i]] + atomicAdd(&cnt[bb[i]], 1);
            ebuf[pos] = pk[i];
        }
    }
}

__global__ void build_csr_kernel(const unsigned* __restrict__ ebuf, const int* __restrict__ boff,
                                 int* __restrict__ rowstart, int* __restrict__ colv,
                                 int n, int E) {
    __shared__ int cnt[256];
    __shared__ int sw[4], sw2[4];
    int t = threadIdx.x, b = blockIdx.x;
    cnt[t] = 0;
    __syncthreads();
    int beg = boff[b], end = boff[b + 1];
    for (int j = beg + t; j < end; j += 256)
        atomicAdd(&cnt[(ebuf[j] >> 17) & 255], 1);
    __syncthreads();
    int v = cnt[t];
    int lane = t & 63, wid = t >> 6;
    int x = v;
#pragma unroll
    for (int off = 1; off < 64; off <<= 1) {
        int y = __shfl_up(x, off, 64);
        if (lane >= off) x += y;
    }
    if (lane == 63) sw[wid] = x;
    __syncthreads();
    if (t == 0) { int a = 0; for (int w = 0; w < 4; ++w) { sw2[w] = a; a += sw[w]; } }
    __syncthreads();
    int excl = x - v + sw2[wid] + beg;
    int node = (b << BSH) + t;
    if (node < n) rowstart[node] = excl;
    if (node == n - 1) rowstart[n] = E;
    __syncthreads();
    cnt[t] = excl;      // reuse as cursor
    __syncthreads();
    for (int j = beg + t; j < end; j += 256) {
        unsigned p = ebuf[j];
        int dlow = (p >> 17) & 255;
        int s = (int)(p & 0x1FFFF);
        int pos = atomicAdd(&cnt[dlow], 1);
        colv[pos] = s;
    }
}

// ---------------- proj1 (MFMA): h(bf16) = x @ W1, fused logits ----------------
// Block = 4 waves, 64 rows/chunk. x chunk + W staged as bf16 in LDS padded to 136
// ushorts/row (bank advance 4/row -> only 2-way aliasing, free). Per wave: 16x
// mfma_f32_16x16x32_bf16 (16 rows x 64 cols, K=128) + 40 ds_read_b64 -- replaces
// ~680 scalar VALU ops/wave of the old path. A/B k-lane-layout cancels between
// operands; D layout (col=lane&15, row=(lane>>4)*4+reg) is the HW-verified one.

__global__ __launch_bounds__(256, 4) void proj1_mfma_kernel(
        const float* __restrict__ x, const float* __restrict__ W,
        const float* __restrict__ a_src, const float* __restrict__ a_dst,
        unsigned short* __restrict__ h, float* __restrict__ as_out,
        float* __restrict__ ad_out, int n) {
    const int PAD = 136;
    __shared__ unsigned short Wt[64 * PAD];    // [n][k] bf16 (transposed W)
    __shared__ unsigned short xsh[64 * PAD];   // [row][k] bf16

    int t = threadIdx.x;
    // stage W transposed: W global row-major [128][64] fp32, coalesced reads
    for (int i = t; i < 128 * 64; i += 256) {
        int k = i >> 6, c = i & 63;
        Wt[c * PAD + k] = f2bf(W[i]);
    }
    // stage x chunk (64 rows x 128), fp32 -> bf16
    int base = blockIdx.x * 64;
    {
        const float4* x4 = reinterpret_cast<const float4*>(x);
        for (int j = t; j < 64 * 32; j += 256) {
            int row = j >> 5, c4 = j & 31;
            int r = base + row;
            float4 v = make_float4(0.f, 0.f, 0.f, 0.f);
            if (r < n) v = x4[(size_t)r * 32 + c4];
            ushort4 pv;
            pv.x = f2bf(v.x); pv.y = f2bf(v.y); pv.z = f2bf(v.z); pv.w = f2bf(v.w);
            *reinterpret_cast<ushort4*>(&xsh[row * PAD + c4 * 4]) = pv;
        }
    }
    __syncthreads();

    int lane = t & 63, wid = t >> 6;
    int q = lane >> 4, m = lane & 15;

    // A fragments: rows wid*16+m, k-blocks of 32
    const unsigned short* xrow = &xsh[(wid * 16 + m) * PAD];
    bf16x8 a[4];
#pragma unroll
    for (int kb = 0; kb < 4; ++kb) {
        ushort4 lo = *reinterpret_cast<const ushort4*>(xrow + kb * 32 + 4 * q);
        ushort4 hi = *reinterpret_cast<const ushort4*>(xrow + kb * 32 + 16 + 4 * q);
        a[kb] = bf16x8{(short)lo.x, (short)lo.y, (short)lo.z, (short)lo.w,
                       (short)hi.x, (short)hi.y, (short)hi.z, (short)hi.w};
    }

    f32x4 acc[4];
#pragma unroll
    for (int ct = 0; ct < 4; ++ct) acc[ct] = f32x4{0.f, 0.f, 0.f, 0.f};
#pragma unroll
    for (int ct = 0; ct < 4; ++ct) {
        const unsigned short* wrow = &Wt[(ct * 16 + m) * PAD];
#pragma unroll
        for (int kb = 0; kb < 4; ++kb) {
            ushort4 lo = *reinterpret_cast<const ushort4*>(wrow + kb * 32 + 4 * q);
            ushort4 hi = *reinterpret_cast<const ushort4*>(wrow + kb * 32 + 16 + 4 * q);
            bf16x8 b = bf16x8{(short)lo.x, (short)lo.y, (short)lo.z, (short)lo.w,
                              (short)hi.x, (short)hi.y, (short)hi.z, (short)hi.w};
            acc[ct] = __builtin_amdgcn_mfma_f32_16x16x32_bf16(a[kb], b, acc[ct], 0, 0, 0);
        }
    }

    // epilogue: h writes + fused attention logits (pre-scaled by log2e)
    float aSL[4], aDL[4];
#pragma unroll
    for (int ct = 0; ct < 4; ++ct) {
        aSL[ct] = a_src[ct * 16 + m] * LOG2E;
        aDL[ct] = a_dst[ct * 16 + m] * LOG2E;
    }
    float s[4] = {0.f, 0.f, 0.f, 0.f}, d[4] = {0.f, 0.f, 0.f, 0.f};
#pragma unroll
    for (int ct = 0; ct < 4; ++ct) {
#pragma unroll
        for (int reg = 0; reg < 4; ++reg) {
            float v = acc[ct][reg];
            int grow = base + wid * 16 + 4 * q + reg;   // D row = (lane>>4)*4+reg
            if (grow < n) h[(size_t)grow * 64 + ct * 16 + m] = f2bf(v);
            s[reg] = fmaf(v, aSL[ct], s[reg]);
            d[reg] = fmaf(v, aDL[ct], d[reg]);
        }
    }
#pragma unroll
    for (int off = 1; off < 16; off <<= 1) {
#pragma unroll
        for (int reg = 0; reg < 4; ++reg) {
            s[reg] += __shfl_xor(s[reg], off, 64);
            d[reg] += __shfl_xor(d[reg], off, 64);
        }
    }
    if (m == 0) {
#pragma unroll
        for (int reg = 0; reg < 4; ++reg) {
            int grow = base + wid * 16 + 4 * q + reg;
            if (grow < n) { as_out[grow] = s[reg]; ad_out[grow] = d[reg]; }
        }
    }
}

// ---------------- proj2: h2(bf16) = z1(packed bf16) @ W2 (+ fused logits) ----------------

__global__ __launch_bounds__(256, 6) void proj2_kernel(
        const unsigned* __restrict__ z1p, const float* __restrict__ W,
        const float* __restrict__ a_src, const float* __restrict__ a_dst,
        __hip_bfloat16* __restrict__ h, float* __restrict__ as_out,
        float* __restrict__ ad_out, int n) {
    const int K = 64;
    __shared__ unsigned Wtp[64 * 33];   // [col][kk] bf16x2, stride 33 (conflict-free)
    __shared__ float xsh[16 * K];       // 16-row z1 chunk, unpacked to fp32

    for (int i = threadIdx.x; i < 32 * 64; i += 256) {
        int kk = i >> 6, c = i & 63;
        unsigned short lo = f2bf(W[(2 * kk) * 64 + c]);
        unsigned short hi = f2bf(W[(2 * kk + 1) * 64 + c]);
        Wtp[c * 33 + kk] = (unsigned)lo | ((unsigned)hi << 16);
    }

    int lane = threadIdx.x & 63, wid = threadIdx.x >> 6;
    float as_l = a_src[lane] * LOG2E, ad_l = a_dst[lane] * LOG2E;
    float4* xsh4 = reinterpret_cast<float4*>(xsh);
    const int K4 = K / 4;
    int nchunk = (n + 15) >> 4;

    for (int ci = blockIdx.x; ci < nchunk; ci += gridDim.x) {
        int base = ci * 16;
        __syncthreads();
        for (int j = threadIdx.x; j < 16 * 32; j += 256) {
            int row = j >> 5, c2 = j & 31;
            int r = base + row;
            unsigned pv = (r < n) ? z1p[(size_t)r * 32 + c2] : 0u;
            xsh[row * K + 2 * c2]     = bf_lo(pv);
            xsh[row * K + 2 * c2 + 1] = bf_hi(pv);
        }
        __syncthreads();

        int r0 = base + wid * 4;
        float acc0 = 0.f, acc1 = 0.f, acc2 = 0.f, acc3 = 0.f;
        const unsigned* wl = Wtp + lane * 33;
#pragma unroll 4
        for (int k4 = 0; k4 < K4; ++k4) {
            float4 va = xsh4[(wid * 4 + 0) * K4 + k4];
            float4 vb = xsh4[(wid * 4 + 1) * K4 + k4];
            float4 vc = xsh4[(wid * 4 + 2) * K4 + k4];
            float4 vd = xsh4[(wid * 4 + 3) * K4 + k4];
            unsigned wp0 = wl[2 * k4], wp1 = wl[2 * k4 + 1];
            float w0 = bf_lo(wp0), w1 = bf_hi(wp0);
            float w2 = bf_lo(wp1), w3 = bf_hi(wp1);
            acc0 = fmaf(va.x, w0, acc0); acc0 = fmaf(va.y, w1, acc0);
            acc0 = fmaf(va.z, w2, acc0); acc0 = fmaf(va.w, w3, acc0);
            acc1 = fmaf(vb.x, w0, acc1); acc1 = fmaf(vb.y, w1, acc1);
            acc1 = fmaf(vb.z, w2, acc1); acc1 = fmaf(vb.w, w3, acc1);
            acc2 = fmaf(vc.x, w0, acc2); acc2 = fmaf(vc.y, w1, acc2);
            acc2 = fmaf(vc.z, w2, acc2); acc2 = fmaf(vc.w, w3, acc2);
            acc3 = fmaf(vd.x, w0, acc3); acc3 = fmaf(vd.y, w1, acc3);
            acc3 = fmaf(vd.z, w2, acc3); acc3 = fmaf(vd.w, w3, acc3);
        }
        if (r0 + 0 < n) h[(size_t)(r0 + 0) * 64 + lane] = __float2bfloat16(acc0);
        if (r0 + 1 < n) h[(size_t)(r0 + 1) * 64 + lane] = __float2bfloat16(acc1);
        if (r0 + 2 < n) h[(size_t)(r0 + 2) * 64 + lane] = __float2bfloat16(acc2);
        if (r0 + 3 < n) h[(size_t)(r0 + 3) * 64 + lane] = __float2bfloat16(acc3);
        float s0 = acc0 * as_l, d0 = acc0 * ad_l;
        float s1 = acc1 * as_l, d1 = acc1 * ad_l;
        float s2 = acc2 * as_l, d2 = acc2 * ad_l;
        float s3 = acc3 * as_l, d3 = acc3 * ad_l;
#pragma unroll
        for (int off = 32; off; off >>= 1) {
            s0 += __shfl_xor(s0, off, 64); d0 += __shfl_xor(d0, off, 64);
            s1 += __shfl_xor(s1, off, 64); d1 += __shfl_xor(d1, off, 64);
            s2 += __shfl_xor(s2, off, 64); d2 += __shfl_xor(d2, off, 64);
            s3 += __shfl_xor(s3, off, 64); d3 += __shfl_xor(d3, off, 64);
        }
        if (lane == 0) {
            if (r0 + 0 < n) { as_out[r0 + 0] = s0; ad_out[r0 + 0] = d0; }
            if (r0 + 1 < n) { as_out[r0 + 1] = s1; ad_out[r0 + 1] = d1; }
            if (r0 + 2 < n) { as_out[r0 + 2] = s2; ad_out[r0 + 2] = d2; }
            if (r0 + 3 < n) { as_out[r0 + 3] = s3; ad_out[r0 + 3] = d3; }
        }
    }
}

// ---------------- Core half-wave agg loop (R17 known-good) ----------------

__device__ inline void agg_core(const unsigned* __restrict__ h32, const float* __restrict__ as_in,
                                float ad_n, int node, int beg, int end, int half, int fl,
                                const int* __restrict__ colv, float& denom, float2& acc) {
    denom = 0.f;
    acc = make_float2(0.f, 0.f);
    if (half == 0) {    // self-loop
        float ex = EXP2F(LRELU(as_in[node] + ad_n));
        unsigned hw = h32[(unsigned)node * 32u + fl];
        denom = ex;
        acc.x = bf_lo(hw) * ex;
        acc.y = bf_hi(hw) * ex;
    }
#define PAIR_STEP(sA, sB)                                             \
    {                                                                 \
        int s_ = half ? (sB) : (sA);                                  \
        bool valid_ = s_ >= 0;                                        \
        int ss_ = valid_ ? s_ : node;                                 \
        float a_ = as_in[ss_];                                        \
        unsigned hw_ = h32[(unsigned)ss_ * 32u + fl];                 \
        float xw_ = valid_ ? EXP2F(LRELU(a_ + ad_n)) : 0.f;           \
        denom += xw_;                                                 \
        acc.x = fmaf(bf_lo(hw_), xw_, acc.x);                         \
        acc.y = fmaf(bf_hi(hw_), xw_, acc.y);                         \
    }
    int i = beg;
    int pre = (beg + 3) & ~3;
    if (pre > end) pre = end;
    while (i < pre) {
        int sA = colv[i];
        bool two = (i + 1 < pre);
        int sB = two ? colv[i + 1] : -1;
        PAIR_STEP(sA, sB);
        i += two ? 2 : 1;
    }
    for (; i + 7 < end; i += 8) {
        int4 cA = *reinterpret_cast<const int4*>(colv + i);
        int4 cB = *reinterpret_cast<const int4*>(colv + i + 4);
        int s0 = half ? cA.y : cA.x;
        int s1 = half ? cA.w : cA.z;
        int s2 = half ? cB.y : cB.x;
        int s3 = half ? cB.w : cB.z;
        float a0 = as_in[s0], a1 = as_in[s1], a2 = as_in[s2], a3 = as_in[s3];
        unsigned w0 = h32[(unsigned)s0 * 32u + fl];
        unsigned w1 = h32[(unsigned)s1 * 32u + fl];
        unsigned w2 = h32[(unsigned)s2 * 32u + fl];
        unsigned w3 = h32[(unsigned)s3 * 32u + fl];
        float x0 = EXP2F(LRELU(a0 + ad_n));
        float x1 = EXP2F(LRELU(a1 + ad_n));
        float x2 = EXP2F(LRELU(a2 + ad_n));
        float x3 = EXP2F(LRELU(a3 + ad_n));
        denom += (x0 + x1) + (x2 + x3);
        acc.x = fmaf(bf_lo(w0), x0, acc.x); acc.y = fmaf(bf_hi(w0), x0, acc.y);
        acc.x = fmaf(bf_lo(w1), x1, acc.x); acc.y = fmaf(bf_hi(w1), x1, acc.y);
        acc.x = fmaf(bf_lo(w2), x2, acc.x); acc.y = fmaf(bf_hi(w2), x2, acc.y);
        acc.x = fmaf(bf_lo(w3), x3, acc.x); acc.y = fmaf(bf_hi(w3), x3, acc.y);
    }
    for (; i + 3 < end; i += 4) {
        int4 cA = *reinterpret_cast<const int4*>(colv + i);
        int s0 = half ? cA.y : cA.x;
        int s1 = half ? cA.w : cA.z;
        float a0 = as_in[s0], a1 = as_in[s1];
        unsigned w0 = h32[(unsigned)s0 * 32u + fl];
        unsigned w1 = h32[(unsigned)s1 * 32u + fl];
        float x0 = EXP2F(LRELU(a0 + ad_n));
        float x1 = EXP2F(LRELU(a1 + ad_n));
        denom += x0 + x1;
        acc.x = fmaf(bf_lo(w0), x0, acc.x); acc.y = fmaf(bf_hi(w0), x0, acc.y);
        acc.x = fmaf(bf_lo(w1), x1, acc.x); acc.y = fmaf(bf_hi(w1), x1, acc.y);
    }
    while (i < end) {
        int sA = colv[i];
        bool two = (i + 1 < end);
        int sB = two ? colv[i + 1] : -1;
        PAIR_STEP(sA, sB);
        i += two ? 2 : 1;
    }
#undef PAIR_STEP
    denom += __shfl_xor(denom, 32, 64);
    acc.x += __shfl_xor(acc.x, 32, 64);
    acc.y += __shfl_xor(acc.y, 32, 64);
}

// ---------------- agg1: softmax-agg + bias + ELU -> packed bf16 z1 ----------------

__global__ void agg1_kernel(const unsigned* __restrict__ h32, const float* __restrict__ as_in,
                            const float* __restrict__ ad_in, const int* __restrict__ rowstart,
                            const int* __restrict__ colv, const float* __restrict__ bias,
                            unsigned* __restrict__ z1p, int n) {
    int node = blockIdx.x * 4 + (int)(threadIdx.x >> 6);
    int lane = threadIdx.x & 63;
    if (node >= n) return;
    int half = lane >> 5, fl = lane & 31;

    float ad_n = ad_in[node];
    int beg = rowstart[node], end = rowstart[node + 1];
    float denom; float2 acc;
    agg_core(h32, as_in, ad_n, node, beg, end, half, fl, colv, denom, acc);

    if (half == 0) {
        float2 bv = *reinterpret_cast<const float2*>(bias + 2 * fl);
        float ox = acc.x / denom + bv.x;
        float oy = acc.y / denom + bv.y;
        ox = ox > 0.f ? ox : __expf(ox) - 1.f;   // ELU
        oy = oy > 0.f ? oy : __expf(oy) - 1.f;
        z1p[(size_t)node * 32 + fl] = (unsigned)f2bf(ox) | ((unsigned)f2bf(oy) << 16);
    }
}

// ---------------- agg2: softmax-agg + bias -> final fp32 output ----------------

__global__ void agg2_kernel(const unsigned* __restrict__ h32, const float* __restrict__ as_in,
                            const float* __restrict__ ad_in, const int* __restrict__ rowstart,
                            const int* __restrict__ colv, const float* __restrict__ bias,
                            float* __restrict__ out, int n) {
    int node = blockIdx.x * 4 + (int)(threadIdx.x >> 6);
    int lane = threadIdx.x & 63;
    if (node >= n) return;
    int half = lane >> 5, fl = lane & 31;

    float ad_n = ad_in[node];
    int beg = rowstart[node], end = rowstart[node + 1];
    float denom; float2 acc;
    agg_core(h32, as_in, ad_n, node, beg, end, half, fl, colv, denom, acc);

    if (half == 0) {
        float2 bv = *reinterpret_cast<const float2*>(bias + 2 * fl);
        float ox = acc.x / denom + bv.x;
        float oy = acc.y / denom + bv.y;
        *reinterpret_cast<float2*>(out + (size_t)node * 64 + 2 * fl) = make_float2(ox, oy);
    }
}

// ---------------- Launch ----------------

extern "C" void kernel_launch(void* const* d_in, const int* in_sizes, int n_in,
                              void* d_out, int out_size, void* d_ws, size_t ws_size,
                              hipStream_t stream) {
    const float* x    = (const float*)d_in[0];
    const int*   eidx = (const int*)d_in[1];   // [2, E] flat
    const float* W1   = (const float*)d_in[2];
    const float* aS1  = (const float*)d_in[3];
    const float* aD1  = (const float*)d_in[4];
    const float* b1   = (const float*)d_in[5];
    const float* W2   = (const float*)d_in[6];
    const float* aS2  = (const float*)d_in[7];
    const float* aD2  = (const float*)d_in[8];
    const float* b2   = (const float*)d_in[9];
    float* out = (float*)d_out;

    const int F = 128, H = 64;
    const int N = in_sizes[0] / F;
    const int E = in_sizes[1] / 2;
    const int* src = eidx;
    const int* dst = eidx + E;

    // workspace carve-up
    char* p = (char*)d_ws;
    __hip_bfloat16* hbuf = (__hip_bfloat16*)p;  p += (size_t)N * H * sizeof(__hip_bfloat16);
    __hip_bfloat16* h2b  = (__hip_bfloat16*)p;  p += (size_t)N * H * sizeof(__hip_bfloat16);
    unsigned* z1p = (unsigned*)p;         p += (size_t)N * (H / 2) * sizeof(unsigned);
    float* as_b  = (float*)p;             p += (size_t)N * sizeof(float);
    float* ad_b  = (float*)p;             p += (size_t)N * sizeof(float);
    float* as2_b = (float*)p;             p += (size_t)N * sizeof(float);
    float* ad2_b = (float*)p;             p += (size_t)N * sizeof(float);
    int* rowstart = (int*)p;              p += (size_t)(N + 4) * sizeof(int);  // pad -> colv 16B-aligned
    int* colv     = (int*)p;              p += (size_t)E * sizeof(int);
    int NB = (N + (1 << BSH) - 1) >> BSH;           // buckets (<= 256)
    int* bhist  = (int*)p;                p += (size_t)NB * sizeof(int);
    int* boff   = (int*)p;                p += (size_t)(NB + 1) * sizeof(int);
    int* bcur   = (int*)p;                p += (size_t)NB * sizeof(int);
    // ebuf aliases hbuf (E*4 B <= N*H*2 B): CSR build fully precedes proj1's h writes.
    unsigned* ebuf = (unsigned*)hbuf;

    int ngrid4 = (N + 3) / 4;
    int nbE = (E + EPB - 1) / EPB;
    int nchunk16 = (N + 15) / 16;
    int nchunk64 = (N + 63) / 64;
    int pgrid = nchunk16 < 1536 ? nchunk16 : 1536;   // proj2 persistent grid

    // --- bucketed CSR build (5 launches) ---
    (void)hipMemsetAsync(bhist, 0, (size_t)NB * sizeof(int), stream);
    hipLaunchKernelGGL(bucket_hist_kernel, dim3(nbE), dim3(256), 0, stream, dst, bhist, E, NB);
    hipLaunchKernelGGL(bucket_scan_kernel, dim3(1), dim3(256), 0, stream, bhist, boff, bcur, NB);
    hipLaunchKernelGGL(bucket_scatter_kernel, dim3(nbE), dim3(256), 0, stream, src, dst, bcur, ebuf, E);
    hipLaunchKernelGGL(build_csr_kernel, dim3(NB), dim3(256), 0, stream, ebuf, boff, rowstart, colv, N, E);

    // --- layer 1 ---
    hipLaunchKernelGGL(proj1_mfma_kernel, dim3(nchunk64), dim3(256), 0, stream,
                       x, W1, aS1, aD1, (unsigned short*)hbuf, as_b, ad_b, N);
    hipLaunchKernelGGL(agg1_kernel, dim3(ngrid4), dim3(256), 0, stream,
                       (const unsigned*)hbuf, as_b, ad_b, rowstart, colv, b1, z1p, N);

    // --- layer 2 ---
    hipLaunchKernelGGL(proj2_kernel, dim3(pgrid), dim3(256), 0, stream,
                       z1p, W2, aS2, aD2, h2b, as2_b, ad2_b, N);
    hipLaunchKernelGGL(agg2_kernel, dim3(ngrid4), dim3(256), 0, stream,
                       (const unsigned*)h2b, as2_b, ad2_b, rowstart, colv, b2, out, N);
}

// Round 21
// 137.567 us; speedup vs baseline: 1.2406x; 1.0627x over previous
//
#include <hip/hip_runtime.h>
#include <hip/hip_bf16.h>

#define LRELU(x) ((x) > 0.f ? (x) : 0.2f * (x))
#define LOG2E 1.44269504088896340736f
#define EXP2F(x) __builtin_amdgcn_exp2f(x)
#define BSH 8          // bucket = 256 consecutive dst nodes (requires N < 131072)
#define EPB 4096       // edges per block in bucket phases

typedef __attribute__((ext_vector_type(8))) short bf16x8;   // MFMA A/B fragment
typedef __attribute__((ext_vector_type(4))) float f32x4;    // MFMA C/D fragment

__device__ inline float bf_lo(unsigned w) { return __uint_as_float(w << 16); }
__device__ inline float bf_hi(unsigned w) { return __uint_as_float(w & 0xffff0000u); }
__device__ inline unsigned short f2bf(float f) {   // round-to-nearest-even bf16
    unsigned u = __float_as_uint(f);
    unsigned r = u + 0x7fffu + ((u >> 16) & 1u);
    return (unsigned short)(r >> 16);
}

// ---------------- fusedA: bucket_hist (blocks [0,nbE)) ∥ proj1 MFMA (rest) ----------------
// The two tasks are independent; fusing removes 2 launch gaps and hides hist (~4us)
// under proj1. LDS is a union (proj1's 34.8KB governs occupancy: 4 blocks/CU).

__global__ __launch_bounds__(256, 4) void fusedA_kernel(
        const int* __restrict__ dst, int* __restrict__ bhist, int E, int NB, int nbE,
        const float* __restrict__ x, const float* __restrict__ W,
        const float* __restrict__ a_src, const float* __restrict__ a_dst,
        unsigned short* __restrict__ h, float* __restrict__ as_out,
        float* __restrict__ ad_out, int n) {
    const int PAD = 136;
    __shared__ union SM {
        int cnt[256];
        unsigned short stage[2 * 64 * 136];   // Wt then xsh
    } sm;

    int t = threadIdx.x;
    if ((int)blockIdx.x < nbE) {
        // ---- bucket histogram ----
        sm.cnt[t] = 0;
        __syncthreads();
        int e0 = blockIdx.x * EPB + t;
#pragma unroll
        for (int i = 0; i < EPB / 256; ++i) {
            int e = e0 + i * 256;
            if (e < E) atomicAdd(&sm.cnt[dst[e] >> BSH], 1);
        }
        __syncthreads();
        if (t < NB && sm.cnt[t]) atomicAdd(&bhist[t], sm.cnt[t]);
        return;
    }

    // ---- proj1 MFMA: 64 rows per block ----
    unsigned short* Wt  = sm.stage;              // [64][PAD] bf16 (transposed W)
    unsigned short* xsh = sm.stage + 64 * PAD;   // [64][PAD] bf16

    for (int i = t; i < 128 * 64; i += 256) {
        int k = i >> 6, c = i & 63;
        Wt[c * PAD + k] = f2bf(W[i]);
    }
    int base = ((int)blockIdx.x - nbE) * 64;
    {
        const float4* x4 = reinterpret_cast<const float4*>(x);
        for (int j = t; j < 64 * 32; j += 256) {
            int row = j >> 5, c4 = j & 31;
            int r = base + row;
            float4 v = make_float4(0.f, 0.f, 0.f, 0.f);
            if (r < n) v = x4[(size_t)r * 32 + c4];
            ushort4 pv;
            pv.x = f2bf(v.x); pv.y = f2bf(v.y); pv.z = f2bf(v.z); pv.w = f2bf(v.w);
            *reinterpret_cast<ushort4*>(&xsh[row * PAD + c4 * 4]) = pv;
        }
    }
    __syncthreads();

    int lane = t & 63, wid = t >> 6;
    int q = lane >> 4, m = lane & 15;

    const unsigned short* xrow = &xsh[(wid * 16 + m) * PAD];
    bf16x8 a[4];
#pragma unroll
    for (int kb = 0; kb < 4; ++kb) {
        ushort4 lo = *reinterpret_cast<const ushort4*>(xrow + kb * 32 + 4 * q);
        ushort4 hi = *reinterpret_cast<const ushort4*>(xrow + kb * 32 + 16 + 4 * q);
        a[kb] = bf16x8{(short)lo.x, (short)lo.y, (short)lo.z, (short)lo.w,
                       (short)hi.x, (short)hi.y, (short)hi.z, (short)hi.w};
    }

    f32x4 acc[4];
#pragma unroll
    for (int ct = 0; ct < 4; ++ct) acc[ct] = f32x4{0.f, 0.f, 0.f, 0.f};
#pragma unroll
    for (int ct = 0; ct < 4; ++ct) {
        const unsigned short* wrow = &Wt[(ct * 16 + m) * PAD];
#pragma unroll
        for (int kb = 0; kb < 4; ++kb) {
            ushort4 lo = *reinterpret_cast<const ushort4*>(wrow + kb * 32 + 4 * q);
            ushort4 hi = *reinterpret_cast<const ushort4*>(wrow + kb * 32 + 16 + 4 * q);
            bf16x8 b = bf16x8{(short)lo.x, (short)lo.y, (short)lo.z, (short)lo.w,
                              (short)hi.x, (short)hi.y, (short)hi.z, (short)hi.w};
            acc[ct] = __builtin_amdgcn_mfma_f32_16x16x32_bf16(a[kb], b, acc[ct], 0, 0, 0);
        }
    }

    float aSL[4], aDL[4];
#pragma unroll
    for (int ct = 0; ct < 4; ++ct) {
        aSL[ct] = a_src[ct * 16 + m] * LOG2E;
        aDL[ct] = a_dst[ct * 16 + m] * LOG2E;
    }
    float s[4] = {0.f, 0.f, 0.f, 0.f}, d[4] = {0.f, 0.f, 0.f, 0.f};
#pragma unroll
    for (int ct = 0; ct < 4; ++ct) {
#pragma unroll
        for (int reg = 0; reg < 4; ++reg) {
            float v = acc[ct][reg];
            int grow = base + wid * 16 + 4 * q + reg;   // D row = (lane>>4)*4+reg
            if (grow < n) h[(size_t)grow * 64 + ct * 16 + m] = f2bf(v);
            s[reg] = fmaf(v, aSL[ct], s[reg]);
            d[reg] = fmaf(v, aDL[ct], d[reg]);
        }
    }
#pragma unroll
    for (int off = 1; off < 16; off <<= 1) {
#pragma unroll
        for (int reg = 0; reg < 4; ++reg) {
            s[reg] += __shfl_xor(s[reg], off, 64);
            d[reg] += __shfl_xor(d[reg], off, 64);
        }
    }
    if (m == 0) {
#pragma unroll
        for (int reg = 0; reg < 4; ++reg) {
            int grow = base + wid * 16 + 4 * q + reg;
            if (grow < n) { as_out[grow] = s[reg]; ad_out[grow] = d[reg]; }
        }
    }
}

// ---------------- scan+scatter fused: every block redundantly scans bhist ----------------
// Block 0 publishes boff; slab cursors are zero-based (bcur0, zeroed by the memset).

__global__ void scan_scatter_kernel(const int* __restrict__ src, const int* __restrict__ dst,
                                    const int* __restrict__ bhist, int* __restrict__ boff,
                                    int* __restrict__ bcur0, unsigned* __restrict__ ebuf,
                                    int E, int NB) {
    __shared__ int cnt[256];
    __shared__ int base[256];
    __shared__ int boffl[256];
    __shared__ int sw[4], sw2[4];
    int t = threadIdx.x;

    // redundant exclusive scan of bucket counts (NB <= 256)
    int v = (t < NB) ? bhist[t] : 0;
    int lane = t & 63, wid = t >> 6;
    int xp = v;
#pragma unroll
    for (int off = 1; off < 64; off <<= 1) {
        int y = __shfl_up(xp, off, 64);
        if (lane >= off) xp += y;
    }
    if (lane == 63) sw[wid] = xp;
    __syncthreads();
    if (t == 0) { int a = 0; for (int w = 0; w < 4; ++w) { sw2[w] = a; a += sw[w]; } }
    __syncthreads();
    int excl = xp - v + sw2[wid];
    boffl[t] = excl;
    if (blockIdx.x == 0) {
        if (t < NB) boff[t] = excl;
        if (t == NB - 1) boff[NB] = excl + v;
    }
    cnt[t] = 0;
    __syncthreads();

    // scatter into per-bucket slabs
    unsigned pk[EPB / 256];
    int bb[EPB / 256];
    int e0 = blockIdx.x * EPB + t;
#pragma unroll
    for (int i = 0; i < EPB / 256; ++i) {
        int e = e0 + i * 256;
        int b = -1; unsigned p = 0;
        if (e < E) {
            int s = src[e], d = dst[e];
            b = d >> BSH;
            p = (unsigned)s | ((unsigned)(d & ((1 << BSH) - 1)) << 17);
            atomicAdd(&cnt[b], 1);
        }
        bb[i] = b; pk[i] = p;
    }
    __syncthreads();
    if (cnt[t]) base[t] = boffl[t] + atomicAdd(&bcur0[t], cnt[t]);
    __syncthreads();
    cnt[t] = 0;
    __syncthreads();
#pragma unroll
    for (int i = 0; i < EPB / 256; ++i) {
        if (bb[i] >= 0) {
            int pos = base[bb[i]] + atomicAdd(&cnt[bb[i]], 1);
            ebuf[pos] = pk[i];
        }
    }
}

// One block per bucket: per-node degree count, in-block scan -> rowstart, scatter colv.
__global__ void build_csr_kernel(const unsigned* __restrict__ ebuf, const int* __restrict__ boff,
                                 int* __restrict__ rowstart, int* __restrict__ colv,
                                 int n, int E) {
    __shared__ int cnt[256];
    __shared__ int sw[4], sw2[4];
    int t = threadIdx.x, b = blockIdx.x;
    cnt[t] = 0;
    __syncthreads();
    int beg = boff[b], end = boff[b + 1];
    for (int j = beg + t; j < end; j += 256)
        atomicAdd(&cnt[(ebuf[j] >> 17) & 255], 1);
    __syncthreads();
    int v = cnt[t];
    int lane = t & 63, wid = t >> 6;
    int x = v;
#pragma unroll
    for (int off = 1; off < 64; off <<= 1) {
        int y = __shfl_up(x, off, 64);
        if (lane >= off) x += y;
    }
    if (lane == 63) sw[wid] = x;
    __syncthreads();
    if (t == 0) { int a = 0; for (int w = 0; w < 4; ++w) { sw2[w] = a; a += sw[w]; } }
    __syncthreads();
    int excl = x - v + sw2[wid] + beg;
    int node = (b << BSH) + t;
    if (node < n) rowstart[node] = excl;
    if (node == n - 1) rowstart[n] = E;
    __syncthreads();
    cnt[t] = excl;      // reuse as cursor
    __syncthreads();
    for (int j = beg + t; j < end; j += 256) {
        unsigned p = ebuf[j];
        int dlow = (p >> 17) & 255;
        int s = (int)(p & 0x1FFFF);
        int pos = atomicAdd(&cnt[dlow], 1);
        colv[pos] = s;
    }
}

// ---------------- proj2: h2(bf16) = z1(packed bf16) @ W2 (+ fused logits) ----------------

__global__ __launch_bounds__(256, 6) void proj2_kernel(
        const unsigned* __restrict__ z1p, const float* __restrict__ W,
        const float* __restrict__ a_src, const float* __restrict__ a_dst,
        __hip_bfloat16* __restrict__ h, float* __restrict__ as_out,
        float* __restrict__ ad_out, int n) {
    const int K = 64;
    __shared__ unsigned Wtp[64 * 33];   // [col][kk] bf16x2, stride 33 (conflict-free)
    __shared__ float xsh[16 * K];       // 16-row z1 chunk, unpacked to fp32

    for (int i = threadIdx.x; i < 32 * 64; i += 256) {
        int kk = i >> 6, c = i & 63;
        unsigned short lo = f2bf(W[(2 * kk) * 64 + c]);
        unsigned short hi = f2bf(W[(2 * kk + 1) * 64 + c]);
        Wtp[c * 33 + kk] = (unsigned)lo | ((unsigned)hi << 16);
    }

    int lane = threadIdx.x & 63, wid = threadIdx.x >> 6;
    float as_l = a_src[lane] * LOG2E, ad_l = a_dst[lane] * LOG2E;
    float4* xsh4 = reinterpret_cast<float4*>(xsh);
    const int K4 = K / 4;
    int nchunk = (n + 15) >> 4;

    for (int ci = blockIdx.x; ci < nchunk; ci += gridDim.x) {
        int base = ci * 16;
        __syncthreads();
        for (int j = threadIdx.x; j < 16 * 32; j += 256) {
            int row = j >> 5, c2 = j & 31;
            int r = base + row;
            unsigned pv = (r < n) ? z1p[(size_t)r * 32 + c2] : 0u;
            xsh[row * K + 2 * c2]     = bf_lo(pv);
            xsh[row * K + 2 * c2 + 1] = bf_hi(pv);
        }
        __syncthreads();

        int r0 = base + wid * 4;
        float acc0 = 0.f, acc1 = 0.f, acc2 = 0.f, acc3 = 0.f;
        const unsigned* wl = Wtp + lane * 33;
#pragma unroll 4
        for (int k4 = 0; k4 < K4; ++k4) {
            float4 va = xsh4[(wid * 4 + 0) * K4 + k4];
            float4 vb = xsh4[(wid * 4 + 1) * K4 + k4];
            float4 vc = xsh4[(wid * 4 + 2) * K4 + k4];
            float4 vd = xsh4[(wid * 4 + 3) * K4 + k4];
            unsigned wp0 = wl[2 * k4], wp1 = wl[2 * k4 + 1];
            float w0 = bf_lo(wp0), w1 = bf_hi(wp0);
            float w2 = bf_lo(wp1), w3 = bf_hi(wp1);
            acc0 = fmaf(va.x, w0, acc0); acc0 = fmaf(va.y, w1, acc0);
            acc0 = fmaf(va.z, w2, acc0); acc0 = fmaf(va.w, w3, acc0);
            acc1 = fmaf(vb.x, w0, acc1); acc1 = fmaf(vb.y, w1, acc1);
            acc1 = fmaf(vb.z, w2, acc1); acc1 = fmaf(vb.w, w3, acc1);
            acc2 = fmaf(vc.x, w0, acc2); acc2 = fmaf(vc.y, w1, acc2);
            acc2 = fmaf(vc.z, w2, acc2); acc2 = fmaf(vc.w, w3, acc2);
            acc3 = fmaf(vd.x, w0, acc3); acc3 = fmaf(vd.y, w1, acc3);
            acc3 = fmaf(vd.z, w2, acc3); acc3 = fmaf(vd.w, w3, acc3);
        }
        if (r0 + 0 < n) h[(size_t)(r0 + 0) * 64 + lane] = __float2bfloat16(acc0);
        if (r0 + 1 < n) h[(size_t)(r0 + 1) * 64 + lane] = __float2bfloat16(acc1);
        if (r0 + 2 < n) h[(size_t)(r0 + 2) * 64 + lane] = __float2bfloat16(acc2);
        if (r0 + 3 < n) h[(size_t)(r0 + 3) * 64 + lane] = __float2bfloat16(acc3);
        float s0 = acc0 * as_l, d0 = acc0 * ad_l;
        float s1 = acc1 * as_l, d1 = acc1 * ad_l;
        float s2 = acc2 * as_l, d2 = acc2 * ad_l;
        float s3 = acc3 * as_l, d3 = acc3 * ad_l;
#pragma unroll
        for (int off = 32; off; off >>= 1) {
            s0 += __shfl_xor(s0, off, 64); d0 += __shfl_xor(d0, off, 64);
            s1 += __shfl_xor(s1, off, 64); d1 += __shfl_xor(d1, off, 64);
            s2 += __shfl_xor(s2, off, 64); d2 += __shfl_xor(d2, off, 64);
            s3 += __shfl_xor(s3, off, 64); d3 += __shfl_xor(d3, off, 64);
        }
        if (lane == 0) {
            if (r0 + 0 < n) { as_out[r0 + 0] = s0; ad_out[r0 + 0] = d0; }
            if (r0 + 1 < n) { as_out[r0 + 1] = s1; ad_out[r0 + 1] = d1; }
            if (r0 + 2 < n) { as_out[r0 + 2] = s2; ad_out[r0 + 2] = d2; }
            if (r0 + 3 < n) { as_out[r0 + 3] = s3; ad_out[r0 + 3] = d3; }
        }
    }
}

// ---------------- Core half-wave agg loop (known-good) ----------------

__device__ inline void agg_core(const unsigned* __restrict__ h32, const float* __restrict__ as_in,
                                float ad_n, int node, int beg, int end, int half, int fl,
                                const int* __restrict__ colv, float& denom, float2& acc) {
    denom = 0.f;
    acc = make_float2(0.f, 0.f);
    if (half == 0) {    // self-loop
        float ex = EXP2F(LRELU(as_in[node] + ad_n));
        unsigned hw = h32[(unsigned)node * 32u + fl];
        denom = ex;
        acc.x = bf_lo(hw) * ex;
        acc.y = bf_hi(hw) * ex;
    }
#define PAIR_STEP(sA, sB)                                             \
    {                                                                 \
        int s_ = half ? (sB) : (sA);                                  \
        bool valid_ = s_ >= 0;                                        \
        int ss_ = valid_ ? s_ : node;                                 \
        float a_ = as_in[ss_];                                        \
        unsigned hw_ = h32[(unsigned)ss_ * 32u + fl];                 \
        float xw_ = valid_ ? EXP2F(LRELU(a_ + ad_n)) : 0.f;           \
        denom += xw_;                                                 \
        acc.x = fmaf(bf_lo(hw_), xw_, acc.x);                         \
        acc.y = fmaf(bf_hi(hw_), xw_, acc.y);                         \
    }
    int i = beg;
    int pre = (beg + 3) & ~3;
    if (pre > end) pre = end;
    while (i < pre) {
        int sA = colv[i];
        bool two = (i + 1 < pre);
        int sB = two ? colv[i + 1] : -1;
        PAIR_STEP(sA, sB);
        i += two ? 2 : 1;
    }
    for (; i + 7 < end; i += 8) {
        int4 cA = *reinterpret_cast<const int4*>(colv + i);
        int4 cB = *reinterpret_cast<const int4*>(colv + i + 4);
        int s0 = half ? cA.y : cA.x;
        int s1 = half ? cA.w : cA.z;
        int s2 = half ? cB.y : cB.x;
        int s3 = half ? cB.w : cB.z;
        float a0 = as_in[s0], a1 = as_in[s1], a2 = as_in[s2], a3 = as_in[s3];
        unsigned w0 = h32[(unsigned)s0 * 32u + fl];
        unsigned w1 = h32[(unsigned)s1 * 32u + fl];
        unsigned w2 = h32[(unsigned)s2 * 32u + fl];
        unsigned w3 = h32[(unsigned)s3 * 32u + fl];
        float x0 = EXP2F(LRELU(a0 + ad_n));
        float x1 = EXP2F(LRELU(a1 + ad_n));
        float x2 = EXP2F(LRELU(a2 + ad_n));
        float x3 = EXP2F(LRELU(a3 + ad_n));
        denom += (x0 + x1) + (x2 + x3);
        acc.x = fmaf(bf_lo(w0), x0, acc.x); acc.y = fmaf(bf_hi(w0), x0, acc.y);
        acc.x = fmaf(bf_lo(w1), x1, acc.x); acc.y = fmaf(bf_hi(w1), x1, acc.y);
        acc.x = fmaf(bf_lo(w2), x2, acc.x); acc.y = fmaf(bf_hi(w2), x2, acc.y);
        acc.x = fmaf(bf_lo(w3), x3, acc.x); acc.y = fmaf(bf_hi(w3), x3, acc.y);
    }
    for (; i + 3 < end; i += 4) {
        int4 cA = *reinterpret_cast<const int4*>(colv + i);
        int s0 = half ? cA.y : cA.x;
        int s1 = half ? cA.w : cA.z;
        float a0 = as_in[s0], a1 = as_in[s1];
        unsigned w0 = h32[(unsigned)s0 * 32u + fl];
        unsigned w1 = h32[(unsigned)s1 * 32u + fl];
        float x0 = EXP2F(LRELU(a0 + ad_n));
        float x1 = EXP2F(LRELU(a1 + ad_n));
        denom += x0 + x1;
        acc.x = fmaf(bf_lo(w0), x0, acc.x); acc.y = fmaf(bf_hi(w0), x0, acc.y);
        acc.x = fmaf(bf_lo(w1), x1, acc.x); acc.y = fmaf(bf_hi(w1), x1, acc.y);
    }
    while (i < end) {
        int sA = colv[i];
        bool two = (i + 1 < end);
        int sB = two ? colv[i + 1] : -1;
        PAIR_STEP(sA, sB);
        i += two ? 2 : 1;
    }
#undef PAIR_STEP
    denom += __shfl_xor(denom, 32, 64);
    acc.x += __shfl_xor(acc.x, 32, 64);
    acc.y += __shfl_xor(acc.y, 32, 64);
}

// ---------------- agg1: softmax-agg + bias + ELU -> packed bf16 z1 ----------------

__global__ void agg1_kernel(const unsigned* __restrict__ h32, const float* __restrict__ as_in,
                            const float* __restrict__ ad_in, const int* __restrict__ rowstart,
                            const int* __restrict__ colv, const float* __restrict__ bias,
                            unsigned* __restrict__ z1p, int n) {
    int node = blockIdx.x * 4 + (int)(threadIdx.x >> 6);
    int lane = threadIdx.x & 63;
    if (node >= n) return;
    int half = lane >> 5, fl = lane & 31;

    float ad_n = ad_in[node];
    int beg = rowstart[node], end = rowstart[node + 1];
    float denom; float2 acc;
    agg_core(h32, as_in, ad_n, node, beg, end, half, fl, colv, denom, acc);

    if (half == 0) {
        float2 bv = *reinterpret_cast<const float2*>(bias + 2 * fl);
        float ox = acc.x / denom + bv.x;
        float oy = acc.y / denom + bv.y;
        ox = ox > 0.f ? ox : __expf(ox) - 1.f;   // ELU
        oy = oy > 0.f ? oy : __expf(oy) - 1.f;
        z1p[(size_t)node * 32 + fl] = (unsigned)f2bf(ox) | ((unsigned)f2bf(oy) << 16);
    }
}

// ---------------- agg2: softmax-agg + bias -> final fp32 output ----------------

__global__ void agg2_kernel(const unsigned* __restrict__ h32, const float* __restrict__ as_in,
                            const float* __restrict__ ad_in, const int* __restrict__ rowstart,
                            const int* __restrict__ colv, const float* __restrict__ bias,
                            float* __restrict__ out, int n) {
    int node = blockIdx.x * 4 + (int)(threadIdx.x >> 6);
    int lane = threadIdx.x & 63;
    if (node >= n) return;
    int half = lane >> 5, fl = lane & 31;

    float ad_n = ad_in[node];
    int beg = rowstart[node], end = rowstart[node + 1];
    float denom; float2 acc;
    agg_core(h32, as_in, ad_n, node, beg, end, half, fl, colv, denom, acc);

    if (half == 0) {
        float2 bv = *reinterpret_cast<const float2*>(bias + 2 * fl);
        float ox = acc.x / denom + bv.x;
        float oy = acc.y / denom + bv.y;
        *reinterpret_cast<float2*>(out + (size_t)node * 64 + 2 * fl) = make_float2(ox, oy);
    }
}

// ---------------- Launch ----------------

extern "C" void kernel_launch(void* const* d_in, const int* in_sizes, int n_in,
                              void* d_out, int out_size, void* d_ws, size_t ws_size,
                              hipStream_t stream) {
    const float* x    = (const float*)d_in[0];
    const int*   eidx = (const int*)d_in[1];   // [2, E] flat
    const float* W1   = (const float*)d_in[2];
    const float* aS1  = (const float*)d_in[3];
    const float* aD1  = (const float*)d_in[4];
    const float* b1   = (const float*)d_in[5];
    const float* W2   = (const float*)d_in[6];
    const float* aS2  = (const float*)d_in[7];
    const float* aD2  = (const float*)d_in[8];
    const float* b2   = (const float*)d_in[9];
    float* out = (float*)d_out;

    const int F = 128, H = 64;
    const int N = in_sizes[0] / F;
    const int E = in_sizes[1] / 2;
    const int* src = eidx;
    const int* dst = eidx + E;

    // workspace carve-up
    char* p = (char*)d_ws;
    __hip_bfloat16* hbuf = (__hip_bfloat16*)p;  p += (size_t)N * H * sizeof(__hip_bfloat16);
    __hip_bfloat16* h2b  = (__hip_bfloat16*)p;  p += (size_t)N * H * sizeof(__hip_bfloat16);
    unsigned* z1p = (unsigned*)p;         p += (size_t)N * (H / 2) * sizeof(unsigned);
    float* as_b  = (float*)p;             p += (size_t)N * sizeof(float);
    float* ad_b  = (float*)p;             p += (size_t)N * sizeof(float);
    float* as2_b = (float*)p;             p += (size_t)N * sizeof(float);
    float* ad2_b = (float*)p;             p += (size_t)N * sizeof(float);
    int* rowstart = (int*)p;              p += (size_t)(N + 4) * sizeof(int);  // pad -> colv 16B-aligned
    int* colv     = (int*)p;              p += (size_t)E * sizeof(int);
    int NB = (N + (1 << BSH) - 1) >> BSH;           // buckets (<= 256)
    int* bhist  = (int*)p;                p += (size_t)NB * sizeof(int);
    int* bcur0  = (int*)p;                p += (size_t)NB * sizeof(int);   // contiguous with bhist
    int* boff   = (int*)p;                p += (size_t)(NB + 1) * sizeof(int);
    // ebuf aliases h2b: scan_scatter writes ebuf, build_csr reads it; proj2
    // overwrites h2b only after build_csr (stream order), when ebuf is dead.
    // E*4 B = 3.2 MB <= N*H*2 B = 6.4 MB. hbuf stays exclusive to proj1/agg1.
    unsigned* ebuf = (unsigned*)h2b;

    int ngrid4 = (N + 3) / 4;
    int nbE = (E + EPB - 1) / EPB;
    int nchunk16 = (N + 15) / 16;
    int nchunk64 = (N + 63) / 64;
    int pgrid = nchunk16 < 1536 ? nchunk16 : 1536;   // proj2 persistent grid

    // --- dispatch chain (7 total) ---
    (void)hipMemsetAsync(bhist, 0, (size_t)(2 * NB) * sizeof(int), stream);  // bhist + bcur0
    // fusedA: bucket_hist (blocks [0,nbE)) ∥ proj1 MFMA (blocks [nbE, nbE+nchunk64))
    hipLaunchKernelGGL(fusedA_kernel, dim3(nbE + nchunk64), dim3(256), 0, stream,
                       dst, bhist, E, NB, nbE,
                       x, W1, aS1, aD1, (unsigned short*)hbuf, as_b, ad_b, N);
    hipLaunchKernelGGL(scan_scatter_kernel, dim3(nbE), dim3(256), 0, stream,
                       src, dst, bhist, boff, bcur0, ebuf, E, NB);
    hipLaunchKernelGGL(build_csr_kernel, dim3(NB), dim3(256), 0, stream,
                       ebuf, boff, rowstart, colv, N, E);
    hipLaunchKernelGGL(agg1_kernel, dim3(ngrid4), dim3(256), 0, stream,
                       (const unsigned*)hbuf, as_b, ad_b, rowstart, colv, b1, z1p, N);
    hipLaunchKernelGGL(proj2_kernel, dim3(pgrid), dim3(256), 0, stream,
                       z1p, W2, aS2, aD2, h2b, as2_b, ad2_b, N);
    hipLaunchKernelGGL(agg2_kernel, dim3(ngrid4), dim3(256), 0, stream,
                       (const unsigned*)h2b, as2_b, ad2_b, rowstart, colv, b2, out, N);
}

// Round 22
// 136.077 us; speedup vs baseline: 1.2541x; 1.0109x over previous
//
#include <hip/hip_runtime.h>
#include <hip/hip_bf16.h>

#define LRELU(x) ((x) > 0.f ? (x) : 0.2f * (x))
#define LOG2E 1.44269504088896340736f
#define EXP2F(x) __builtin_amdgcn_exp2f(x)
#define BSH 8          // bucket = 256 consecutive dst nodes (requires N < 131072)
#define EPB 4096       // edges per block in bucket phases

typedef __attribute__((ext_vector_type(8))) short bf16x8;   // MFMA A/B fragment
typedef __attribute__((ext_vector_type(4))) float f32x4;    // MFMA C/D fragment

__device__ inline float bf_lo(unsigned w) { return __uint_as_float(w << 16); }
__device__ inline float bf_hi(unsigned w) { return __uint_as_float(w & 0xffff0000u); }
__device__ inline unsigned short f2bf(float f) {   // round-to-nearest-even bf16
    unsigned u = __float_as_uint(f);
    unsigned r = u + 0x7fffu + ((u >> 16) & 1u);
    return (unsigned short)(r >> 16);
}

// ---------------- fusedA: bucket_hist (blocks [0,nbE)) ∥ proj1 MFMA (rest) ----------------

__global__ __launch_bounds__(256, 4) void fusedA_kernel(
        const int* __restrict__ dst, int* __restrict__ bhist, int E, int NB, int nbE,
        const float* __restrict__ x, const float* __restrict__ W,
        const float* __restrict__ a_src, const float* __restrict__ a_dst,
        unsigned short* __restrict__ h, float* __restrict__ as_out,
        float* __restrict__ ad_out, int n) {
    const int PAD = 136;
    __shared__ union SM {
        int cnt[256];
        unsigned short stage[2 * 64 * 136];   // Wt then xsh
    } sm;

    int t = threadIdx.x;
    if ((int)blockIdx.x < nbE) {
        // ---- bucket histogram ----
        sm.cnt[t] = 0;
        __syncthreads();
        int e0 = blockIdx.x * EPB + t;
#pragma unroll
        for (int i = 0; i < EPB / 256; ++i) {
            int e = e0 + i * 256;
            if (e < E) atomicAdd(&sm.cnt[dst[e] >> BSH], 1);
        }
        __syncthreads();
        if (t < NB && sm.cnt[t]) atomicAdd(&bhist[t], sm.cnt[t]);
        return;
    }

    // ---- proj1 MFMA: 64 rows per block ----
    unsigned short* Wt  = sm.stage;              // [64][PAD] bf16 (transposed W)
    unsigned short* xsh = sm.stage + 64 * PAD;   // [64][PAD] bf16

    for (int i = t; i < 128 * 64; i += 256) {
        int k = i >> 6, c = i & 63;
        Wt[c * PAD + k] = f2bf(W[i]);
    }
    int base = ((int)blockIdx.x - nbE) * 64;
    {
        const float4* x4 = reinterpret_cast<const float4*>(x);
        for (int j = t; j < 64 * 32; j += 256) {
            int row = j >> 5, c4 = j & 31;
            int r = base + row;
            float4 v = make_float4(0.f, 0.f, 0.f, 0.f);
            if (r < n) v = x4[(size_t)r * 32 + c4];
            ushort4 pv;
            pv.x = f2bf(v.x); pv.y = f2bf(v.y); pv.z = f2bf(v.z); pv.w = f2bf(v.w);
            *reinterpret_cast<ushort4*>(&xsh[row * PAD + c4 * 4]) = pv;
        }
    }
    __syncthreads();

    int lane = t & 63, wid = t >> 6;
    int q = lane >> 4, m = lane & 15;

    const unsigned short* xrow = &xsh[(wid * 16 + m) * PAD];
    bf16x8 a[4];
#pragma unroll
    for (int kb = 0; kb < 4; ++kb) {
        ushort4 lo = *reinterpret_cast<const ushort4*>(xrow + kb * 32 + 4 * q);
        ushort4 hi = *reinterpret_cast<const ushort4*>(xrow + kb * 32 + 16 + 4 * q);
        a[kb] = bf16x8{(short)lo.x, (short)lo.y, (short)lo.z, (short)lo.w,
                       (short)hi.x, (short)hi.y, (short)hi.z, (short)hi.w};
    }

    f32x4 acc[4];
#pragma unroll
    for (int ct = 0; ct < 4; ++ct) acc[ct] = f32x4{0.f, 0.f, 0.f, 0.f};
#pragma unroll
    for (int ct = 0; ct < 4; ++ct) {
        const unsigned short* wrow = &Wt[(ct * 16 + m) * PAD];
#pragma unroll
        for (int kb = 0; kb < 4; ++kb) {
            ushort4 lo = *reinterpret_cast<const ushort4*>(wrow + kb * 32 + 4 * q);
            ushort4 hi = *reinterpret_cast<const ushort4*>(wrow + kb * 32 + 16 + 4 * q);
            bf16x8 b = bf16x8{(short)lo.x, (short)lo.y, (short)lo.z, (short)lo.w,
                              (short)hi.x, (short)hi.y, (short)hi.z, (short)hi.w};
            acc[ct] = __builtin_amdgcn_mfma_f32_16x16x32_bf16(a[kb], b, acc[ct], 0, 0, 0);
        }
    }

    float aSL[4], aDL[4];
#pragma unroll
    for (int ct = 0; ct < 4; ++ct) {
        aSL[ct] = a_src[ct * 16 + m] * LOG2E;
        aDL[ct] = a_dst[ct * 16 + m] * LOG2E;
    }
    float s[4] = {0.f, 0.f, 0.f, 0.f}, d[4] = {0.f, 0.f, 0.f, 0.f};
#pragma unroll
    for (int ct = 0; ct < 4; ++ct) {
#pragma unroll
        for (int reg = 0; reg < 4; ++reg) {
            float v = acc[ct][reg];
            int grow = base + wid * 16 + 4 * q + reg;   // D row = (lane>>4)*4+reg
            if (grow < n) h[(size_t)grow * 64 + ct * 16 + m] = f2bf(v);
            s[reg] = fmaf(v, aSL[ct], s[reg]);
            d[reg] = fmaf(v, aDL[ct], d[reg]);
        }
    }
#pragma unroll
    for (int off = 1; off < 16; off <<= 1) {
#pragma unroll
        for (int reg = 0; reg < 4; ++reg) {
            s[reg] += __shfl_xor(s[reg], off, 64);
            d[reg] += __shfl_xor(d[reg], off, 64);
        }
    }
    if (m == 0) {
#pragma unroll
        for (int reg = 0; reg < 4; ++reg) {
            int grow = base + wid * 16 + 4 * q + reg;
            if (grow < n) { as_out[grow] = s[reg]; ad_out[grow] = d[reg]; }
        }
    }
}

// ---------------- scan+scatter fused ----------------

__global__ void scan_scatter_kernel(const int* __restrict__ src, const int* __restrict__ dst,
                                    const int* __restrict__ bhist, int* __restrict__ boff,
                                    int* __restrict__ bcur0, unsigned* __restrict__ ebuf,
                                    int E, int NB) {
    __shared__ int cnt[256];
    __shared__ int base[256];
    __shared__ int boffl[256];
    __shared__ int sw[4], sw2[4];
    int t = threadIdx.x;

    int v = (t < NB) ? bhist[t] : 0;
    int lane = t & 63, wid = t >> 6;
    int xp = v;
#pragma unroll
    for (int off = 1; off < 64; off <<= 1) {
        int y = __shfl_up(xp, off, 64);
        if (lane >= off) xp += y;
    }
    if (lane == 63) sw[wid] = xp;
    __syncthreads();
    if (t == 0) { int a = 0; for (int w = 0; w < 4; ++w) { sw2[w] = a; a += sw[w]; } }
    __syncthreads();
    int excl = xp - v + sw2[wid];
    boffl[t] = excl;
    if (blockIdx.x == 0) {
        if (t < NB) boff[t] = excl;
        if (t == NB - 1) boff[NB] = excl + v;
    }
    cnt[t] = 0;
    __syncthreads();

    unsigned pk[EPB / 256];
    int bb[EPB / 256];
    int e0 = blockIdx.x * EPB + t;
#pragma unroll
    for (int i = 0; i < EPB / 256; ++i) {
        int e = e0 + i * 256;
        int b = -1; unsigned p = 0;
        if (e < E) {
            int s = src[e], d = dst[e];
            b = d >> BSH;
            p = (unsigned)s | ((unsigned)(d & ((1 << BSH) - 1)) << 17);
            atomicAdd(&cnt[b], 1);
        }
        bb[i] = b; pk[i] = p;
    }
    __syncthreads();
    if (cnt[t]) base[t] = boffl[t] + atomicAdd(&bcur0[t], cnt[t]);
    __syncthreads();
    cnt[t] = 0;
    __syncthreads();
#pragma unroll
    for (int i = 0; i < EPB / 256; ++i) {
        if (bb[i] >= 0) {
            int pos = base[bb[i]] + atomicAdd(&cnt[bb[i]], 1);
            ebuf[pos] = pk[i];
        }
    }
}

// One block per bucket: per-node degree count, in-block scan -> rowstart, scatter colv.
__global__ void build_csr_kernel(const unsigned* __restrict__ ebuf, const int* __restrict__ boff,
                                 int* __restrict__ rowstart, int* __restrict__ colv,
                                 int n, int E) {
    __shared__ int cnt[256];
    __shared__ int sw[4], sw2[4];
    int t = threadIdx.x, b = blockIdx.x;
    cnt[t] = 0;
    __syncthreads();
    int beg = boff[b], end = boff[b + 1];
    for (int j = beg + t; j < end; j += 256)
        atomicAdd(&cnt[(ebuf[j] >> 17) & 255], 1);
    __syncthreads();
    int v = cnt[t];
    int lane = t & 63, wid = t >> 6;
    int x = v;
#pragma unroll
    for (int off = 1; off < 64; off <<= 1) {
        int y = __shfl_up(x, off, 64);
        if (lane >= off) x += y;
    }
    if (lane == 63) sw[wid] = x;
    __syncthreads();
    if (t == 0) { int a = 0; for (int w = 0; w < 4; ++w) { sw2[w] = a; a += sw[w]; } }
    __syncthreads();
    int excl = x - v + sw2[wid] + beg;
    int node = (b << BSH) + t;
    if (node < n) rowstart[node] = excl;
    if (node == n - 1) rowstart[n] = E;
    __syncthreads();
    cnt[t] = excl;      // reuse as cursor
    __syncthreads();
    for (int j = beg + t; j < end; j += 256) {
        unsigned p = ebuf[j];
        int dlow = (p >> 17) & 255;
        int s = (int)(p & 0x1FFFF);
        int pos = atomicAdd(&cnt[dlow], 1);
        colv[pos] = s;
    }
}

// ---------------- proj2: h2(bf16) = z1(packed bf16) @ W2 (+ fused logits) ----------------

__global__ __launch_bounds__(256, 6) void proj2_kernel(
        const unsigned* __restrict__ z1p, const float* __restrict__ W,
        const float* __restrict__ a_src, const float* __restrict__ a_dst,
        __hip_bfloat16* __restrict__ h, float* __restrict__ as_out,
        float* __restrict__ ad_out, int n) {
    const int K = 64;
    __shared__ unsigned Wtp[64 * 33];   // [col][kk] bf16x2, stride 33 (conflict-free)
    __shared__ float xsh[16 * K];       // 16-row z1 chunk, unpacked to fp32

    for (int i = threadIdx.x; i < 32 * 64; i += 256) {
        int kk = i >> 6, c = i & 63;
        unsigned short lo = f2bf(W[(2 * kk) * 64 + c]);
        unsigned short hi = f2bf(W[(2 * kk + 1) * 64 + c]);
        Wtp[c * 33 + kk] = (unsigned)lo | ((unsigned)hi << 16);
    }

    int lane = threadIdx.x & 63, wid = threadIdx.x >> 6;
    float as_l = a_src[lane] * LOG2E, ad_l = a_dst[lane] * LOG2E;
    float4* xsh4 = reinterpret_cast<float4*>(xsh);
    const int K4 = K / 4;
    int nchunk = (n + 15) >> 4;

    for (int ci = blockIdx.x; ci < nchunk; ci += gridDim.x) {
        int base = ci * 16;
        __syncthreads();
        for (int j = threadIdx.x; j < 16 * 32; j += 256) {
            int row = j >> 5, c2 = j & 31;
            int r = base + row;
            unsigned pv = (r < n) ? z1p[(size_t)r * 32 + c2] : 0u;
            xsh[row * K + 2 * c2]     = bf_lo(pv);
            xsh[row * K + 2 * c2 + 1] = bf_hi(pv);
        }
        __syncthreads();

        int r0 = base + wid * 4;
        float acc0 = 0.f, acc1 = 0.f, acc2 = 0.f, acc3 = 0.f;
        const unsigned* wl = Wtp + lane * 33;
#pragma unroll 4
        for (int k4 = 0; k4 < K4; ++k4) {
            float4 va = xsh4[(wid * 4 + 0) * K4 + k4];
            float4 vb = xsh4[(wid * 4 + 1) * K4 + k4];
            float4 vc = xsh4[(wid * 4 + 2) * K4 + k4];
            float4 vd = xsh4[(wid * 4 + 3) * K4 + k4];
            unsigned wp0 = wl[2 * k4], wp1 = wl[2 * k4 + 1];
            float w0 = bf_lo(wp0), w1 = bf_hi(wp0);
            float w2 = bf_lo(wp1), w3 = bf_hi(wp1);
            acc0 = fmaf(va.x, w0, acc0); acc0 = fmaf(va.y, w1, acc0);
            acc0 = fmaf(va.z, w2, acc0); acc0 = fmaf(va.w, w3, acc0);
            acc1 = fmaf(vb.x, w0, acc1); acc1 = fmaf(vb.y, w1, acc1);
            acc1 = fmaf(vb.z, w2, acc1); acc1 = fmaf(vb.w, w3, acc1);
            acc2 = fmaf(vc.x, w0, acc2); acc2 = fmaf(vc.y, w1, acc2);
            acc2 = fmaf(vc.z, w2, acc2); acc2 = fmaf(vc.w, w3, acc2);
            acc3 = fmaf(vd.x, w0, acc3); acc3 = fmaf(vd.y, w1, acc3);
            acc3 = fmaf(vd.z, w2, acc3); acc3 = fmaf(vd.w, w3, acc3);
        }
        if (r0 + 0 < n) h[(size_t)(r0 + 0) * 64 + lane] = __float2bfloat16(acc0);
        if (r0 + 1 < n) h[(size_t)(r0 + 1) * 64 + lane] = __float2bfloat16(acc1);
        if (r0 + 2 < n) h[(size_t)(r0 + 2) * 64 + lane] = __float2bfloat16(acc2);
        if (r0 + 3 < n) h[(size_t)(r0 + 3) * 64 + lane] = __float2bfloat16(acc3);
        float s0 = acc0 * as_l, d0 = acc0 * ad_l;
        float s1 = acc1 * as_l, d1 = acc1 * ad_l;
        float s2 = acc2 * as_l, d2 = acc2 * ad_l;
        float s3 = acc3 * as_l, d3 = acc3 * ad_l;
#pragma unroll
        for (int off = 32; off; off >>= 1) {
            s0 += __shfl_xor(s0, off, 64); d0 += __shfl_xor(d0, off, 64);
            s1 += __shfl_xor(s1, off, 64); d1 += __shfl_xor(d1, off, 64);
            s2 += __shfl_xor(s2, off, 64); d2 += __shfl_xor(d2, off, 64);
            s3 += __shfl_xor(s3, off, 64); d3 += __shfl_xor(d3, off, 64);
        }
        if (lane == 0) {
            if (r0 + 0 < n) { as_out[r0 + 0] = s0; ad_out[r0 + 0] = d0; }
            if (r0 + 1 < n) { as_out[r0 + 1] = s1; ad_out[r0 + 1] = d1; }
            if (r0 + 2 < n) { as_out[r0 + 2] = s2; ad_out[r0 + 2] = d2; }
            if (r0 + 3 < n) { as_out[r0 + 3] = s3; ad_out[r0 + 3] = d3; }
        }
    }
}

// ---------------- Core half-wave agg loop, 16-edge batches ----------------
// 16 edges in flight (4 int4 colv + 16 as + 16 h gathers) -- typical node degree
// ~17, so most nodes complete in ONE memory round-trip instead of 2-3.

__device__ inline void agg_core(const unsigned* __restrict__ h32, const float* __restrict__ as_in,
                                float ad_n, int node, int beg, int end, int half, int fl,
                                const int* __restrict__ colv, float& denom, float2& acc) {
    denom = 0.f;
    acc = make_float2(0.f, 0.f);
    if (half == 0) {    // self-loop
        float ex = EXP2F(LRELU(as_in[node] + ad_n));
        unsigned hw = h32[(unsigned)node * 32u + fl];
        denom = ex;
        acc.x = bf_lo(hw) * ex;
        acc.y = bf_hi(hw) * ex;
    }
#define PAIR_STEP(sA, sB)                                             \
    {                                                                 \
        int s_ = half ? (sB) : (sA);                                  \
        bool valid_ = s_ >= 0;                                        \
        int ss_ = valid_ ? s_ : node;                                 \
        float a_ = as_in[ss_];                                        \
        unsigned hw_ = h32[(unsigned)ss_ * 32u + fl];                 \
        float xw_ = valid_ ? EXP2F(LRELU(a_ + ad_n)) : 0.f;           \
        denom += xw_;                                                 \
        acc.x = fmaf(bf_lo(hw_), xw_, acc.x);                         \
        acc.y = fmaf(bf_hi(hw_), xw_, acc.y);                         \
    }
#define EDGE4(c4)                                                     \
    {                                                                 \
        int s0 = half ? (c4).y : (c4).x;                              \
        int s1 = half ? (c4).w : (c4).z;                              \
        float a0 = as_in[s0], a1 = as_in[s1];                         \
        unsigned w0 = h32[(unsigned)s0 * 32u + fl];                   \
        unsigned w1 = h32[(unsigned)s1 * 32u + fl];                   \
        float x0 = EXP2F(LRELU(a0 + ad_n));                           \
        float x1 = EXP2F(LRELU(a1 + ad_n));                           \
        denom += x0 + x1;                                             \
        acc.x = fmaf(bf_lo(w0), x0, acc.x); acc.y = fmaf(bf_hi(w0), x0, acc.y); \
        acc.x = fmaf(bf_lo(w1), x1, acc.x); acc.y = fmaf(bf_hi(w1), x1, acc.y); \
    }
    int i = beg;
    int pre = (beg + 3) & ~3;
    if (pre > end) pre = end;
    while (i < pre) {
        int sA = colv[i];
        bool two = (i + 1 < pre);
        int sB = two ? colv[i + 1] : -1;
        PAIR_STEP(sA, sB);
        i += two ? 2 : 1;
    }
    for (; i + 15 < end; i += 16) {   // 16 edges = 4 aligned int4 loads, all in flight
        int4 cA = *reinterpret_cast<const int4*>(colv + i);
        int4 cB = *reinterpret_cast<const int4*>(colv + i + 4);
        int4 cC = *reinterpret_cast<const int4*>(colv + i + 8);
        int4 cD = *reinterpret_cast<const int4*>(colv + i + 12);
        EDGE4(cA); EDGE4(cB); EDGE4(cC); EDGE4(cD);
    }
    for (; i + 7 < end; i += 8) {
        int4 cA = *reinterpret_cast<const int4*>(colv + i);
        int4 cB = *reinterpret_cast<const int4*>(colv + i + 4);
        EDGE4(cA); EDGE4(cB);
    }
    for (; i + 3 < end; i += 4) {
        int4 cA = *reinterpret_cast<const int4*>(colv + i);
        EDGE4(cA);
    }
    while (i < end) {
        int sA = colv[i];
        bool two = (i + 1 < end);
        int sB = two ? colv[i + 1] : -1;
        PAIR_STEP(sA, sB);
        i += two ? 2 : 1;
    }
#undef EDGE4
#undef PAIR_STEP
    denom += __shfl_xor(denom, 32, 64);
    acc.x += __shfl_xor(acc.x, 32, 64);
    acc.y += __shfl_xor(acc.y, 32, 64);
}

// ---------------- agg1: softmax-agg + bias + ELU -> packed bf16 z1 ----------------

__global__ void agg1_kernel(const unsigned* __restrict__ h32, const float* __restrict__ as_in,
                            const float* __restrict__ ad_in, const int* __restrict__ rowstart,
                            const int* __restrict__ colv, const float* __restrict__ bias,
                            unsigned* __restrict__ z1p, int n) {
    int node = blockIdx.x * 4 + (int)(threadIdx.x >> 6);
    int lane = threadIdx.x & 63;
    if (node >= n) return;
    int half = lane >> 5, fl = lane & 31;

    float ad_n = ad_in[node];
    int beg = rowstart[node], end = rowstart[node + 1];
    float denom; float2 acc;
    agg_core(h32, as_in, ad_n, node, beg, end, half, fl, colv, denom, acc);

    if (half == 0) {
        float2 bv = *reinterpret_cast<const float2*>(bias + 2 * fl);
        float ox = acc.x / denom + bv.x;
        float oy = acc.y / denom + bv.y;
        ox = ox > 0.f ? ox : __expf(ox) - 1.f;   // ELU
        oy = oy > 0.f ? oy : __expf(oy) - 1.f;
        z1p[(size_t)node * 32 + fl] = (unsigned)f2bf(ox) | ((unsigned)f2bf(oy) << 16);
    }
}

// ---------------- agg2: softmax-agg + bias -> final fp32 output ----------------

__global__ void agg2_kernel(const unsigned* __restrict__ h32, const float* __restrict__ as_in,
                            const float* __restrict__ ad_in, const int* __restrict__ rowstart,
                            const int* __restrict__ colv, const float* __restrict__ bias,
                            float* __restrict__ out, int n) {
    int node = blockIdx.x * 4 + (int)(threadIdx.x >> 6);
    int lane = threadIdx.x & 63;
    if (node >= n) return;
    int half = lane >> 5, fl = lane & 31;

    float ad_n = ad_in[node];
    int beg = rowstart[node], end = rowstart[node + 1];
    float denom; float2 acc;
    agg_core(h32, as_in, ad_n, node, beg, end, half, fl, colv, denom, acc);

    if (half == 0) {
        float2 bv = *reinterpret_cast<const float2*>(bias + 2 * fl);
        float ox = acc.x / denom + bv.x;
        float oy = acc.y / denom + bv.y;
        *reinterpret_cast<float2*>(out + (size_t)node * 64 + 2 * fl) = make_float2(ox, oy);
    }
}

// ---------------- Launch ----------------

extern "C" void kernel_launch(void* const* d_in, const int* in_sizes, int n_in,
                              void* d_out, int out_size, void* d_ws, size_t ws_size,
                              hipStream_t stream) {
    const float* x    = (const float*)d_in[0];
    const int*   eidx = (const int*)d_in[1];   // [2, E] flat
    const float* W1   = (const float*)d_in[2];
    const float* aS1  = (const float*)d_in[3];
    const float* aD1  = (const float*)d_in[4];
    const float* b1   = (const float*)d_in[5];
    const float* W2   = (const float*)d_in[6];
    const float* aS2  = (const float*)d_in[7];
    const float* aD2  = (const float*)d_in[8];
    const float* b2   = (const float*)d_in[9];
    float* out = (float*)d_out;

    const int F = 128, H = 64;
    const int N = in_sizes[0] / F;
    const int E = in_sizes[1] / 2;
    const int* src = eidx;
    const int* dst = eidx + E;

    // workspace carve-up
    char* p = (char*)d_ws;
    __hip_bfloat16* hbuf = (__hip_bfloat16*)p;  p += (size_t)N * H * sizeof(__hip_bfloat16);
    __hip_bfloat16* h2b  = (__hip_bfloat16*)p;  p += (size_t)N * H * sizeof(__hip_bfloat16);
    unsigned* z1p = (unsigned*)p;         p += (size_t)N * (H / 2) * sizeof(unsigned);
    float* as_b  = (float*)p;             p += (size_t)N * sizeof(float);
    float* ad_b  = (float*)p;             p += (size_t)N * sizeof(float);
    float* as2_b = (float*)p;             p += (size_t)N * sizeof(float);
    float* ad2_b = (float*)p;             p += (size_t)N * sizeof(float);
    int* rowstart = (int*)p;              p += (size_t)(N + 4) * sizeof(int);  // pad -> colv 16B-aligned
    int* colv     = (int*)p;              p += (size_t)E * sizeof(int);
    int NB = (N + (1 << BSH) - 1) >> BSH;           // buckets (<= 256)
    int* bhist  = (int*)p;                p += (size_t)NB * sizeof(int);
    int* bcur0  = (int*)p;                p += (size_t)NB * sizeof(int);   // contiguous with bhist
    int* boff   = (int*)p;                p += (size_t)(NB + 1) * sizeof(int);
    // ebuf aliases h2b: scan_scatter writes ebuf, build_csr reads it; proj2
    // overwrites h2b only after build_csr (stream order), when ebuf is dead.
    unsigned* ebuf = (unsigned*)h2b;

    int ngrid4 = (N + 3) / 4;
    int nbE = (E + EPB - 1) / EPB;
    int nchunk16 = (N + 15) / 16;
    int nchunk64 = (N + 63) / 64;
    int pgrid = nchunk16 < 1536 ? nchunk16 : 1536;   // proj2 persistent grid

    // --- dispatch chain (7 total) ---
    (void)hipMemsetAsync(bhist, 0, (size_t)(2 * NB) * sizeof(int), stream);  // bhist + bcur0
    hipLaunchKernelGGL(fusedA_kernel, dim3(nbE + nchunk64), dim3(256), 0, stream,
                       dst, bhist, E, NB, nbE,
                       x, W1, aS1, aD1, (unsigned short*)hbuf, as_b, ad_b, N);
    hipLaunchKernelGGL(scan_scatter_kernel, dim3(nbE), dim3(256), 0, stream,
                       src, dst, bhist, boff, bcur0, ebuf, E, NB);
    hipLaunchKernelGGL(build_csr_kernel, dim3(NB), dim3(256), 0, stream,
                       ebuf, boff, rowstart, colv, N, E);
    hipLaunchKernelGGL(agg1_kernel, dim3(ngrid4), dim3(256), 0, stream,
                       (const unsigned*)hbuf, as_b, ad_b, rowstart, colv, b1, z1p, N);
    hipLaunchKernelGGL(proj2_kernel, dim3(pgrid), dim3(256), 0, stream,
                       z1p, W2, aS2, aD2, h2b, as2_b, ad2_b, N);
    hipLaunchKernelGGL(agg2_kernel, dim3(ngrid4), dim3(256), 0, stream,
                       (const unsigned*)h2b, as2_b, ad2_b, rowstart, colv, b2, out, N);
}